// Round 1
// baseline (1043.711 us; speedup 1.0000x reference)
//
#include <hip/hip_runtime.h>
#include <math.h>

#define NN 100000       // N_NODES
#define NE 800000       // N_EDGES
#define DN 64           // D_NODE
#define DE 4            // D_EDGE
#define HH 128          // H_MSG == H_UPD

// ---------------------------------------------------------------------------
// Kernel 1: per-node projections  XA = x @ W1[0:64,:], XB = x @ W1[64:128,:]
// One block (256 threads) per node: threads 0..127 -> XA, 128..255 -> XB.
// ---------------------------------------------------------------------------
__global__ __launch_bounds__(256) void k_xproj(const float* __restrict__ x,
                                               const float* __restrict__ W1,
                                               float* __restrict__ XA,
                                               float* __restrict__ XB) {
    __shared__ float xs[DN];
    const int n = blockIdx.x;
    const int t = threadIdx.x;
    if (t < DN) xs[t] = x[(size_t)n * DN + t];
    __syncthreads();
    const int j = t & 127;
    const float* w = (t < 128) ? (W1 + j) : (W1 + 64 * HH + j);
    float acc = 0.f;
#pragma unroll
    for (int k = 0; k < DN; ++k) acc = fmaf(xs[k], w[(size_t)k * HH], acc);
    if (t < 128) XA[(size_t)n * HH + j] = acc;
    else         XB[(size_t)n * HH + j] = acc;
}

// ---------------------------------------------------------------------------
// Kernel 2: per-edge hidden + scatter-add.
// One wave (64 lanes) per edge; each lane handles hidden dims {lane, lane+64}.
//   h = relu(XA[s] + XB[d] + log1p(ef) @ W1[128:132,:] + b1)
//   Hagg[d] += h (atomic), deg[d] += 1
// ---------------------------------------------------------------------------
__global__ __launch_bounds__(256) void k_edge(const int* __restrict__ ei,
                                              const float* __restrict__ ef,
                                              const float* __restrict__ W1,
                                              const float* __restrict__ b1,
                                              const float* __restrict__ XA,
                                              const float* __restrict__ XB,
                                              float* __restrict__ Hagg,
                                              float* __restrict__ deg) {
    const int wave = threadIdx.x >> 6;
    const int lane = threadIdx.x & 63;
    const long e = (long)blockIdx.x * 4 + wave;
    if (e >= NE) return;
    const int s = ei[e];
    const int d = ei[NE + e];

    float t = 0.f;
    if (lane < DE) t = log1pf(ef[e * DE + lane]);
    const float l0 = __shfl(t, 0);
    const float l1 = __shfl(t, 1);
    const float l2 = __shfl(t, 2);
    const float l3 = __shfl(t, 3);

    const float* we = W1 + 128 * HH;   // W1[128:132,:]
    const size_t sb = (size_t)s * HH;
    const size_t db = (size_t)d * HH;
#pragma unroll
    for (int r = 0; r < 2; ++r) {
        const int j = lane + r * 64;
        float h = XA[sb + j] + XB[db + j] + b1[j];
        h = fmaf(l0, we[0 * HH + j], h);
        h = fmaf(l1, we[1 * HH + j], h);
        h = fmaf(l2, we[2 * HH + j], h);
        h = fmaf(l3, we[3 * HH + j], h);
        h = fmaxf(h, 0.f);
        atomicAdd(&Hagg[db + j], h);
    }
    if (lane == 0) atomicAdd(&deg[d], 1.f);
}

// ---------------------------------------------------------------------------
// Kernel 3: per-node second message GEMM + update MLP, fused.
//   agg = Hagg @ W2 + deg*b2            (64 dims)
//   u   = relu([x, agg] @ U1 + bu1)     (128 dims)
//   out = u @ U2 + bu2                  (64 dims)
// One block (128 threads) per node.
// ---------------------------------------------------------------------------
__global__ __launch_bounds__(128) void k_update(const float* __restrict__ x,
                                                const float* __restrict__ Hagg,
                                                const float* __restrict__ deg,
                                                const float* __restrict__ W2,
                                                const float* __restrict__ b2,
                                                const float* __restrict__ U1,
                                                const float* __restrict__ bu1,
                                                const float* __restrict__ U2,
                                                const float* __restrict__ bu2,
                                                float* __restrict__ out) {
    __shared__ float hrow[HH];
    __shared__ float xrow[DN];
    __shared__ float aggs[DN];
    __shared__ float um[HH];
    const int n = blockIdx.x;
    const int t = threadIdx.x;

    hrow[t] = Hagg[(size_t)n * HH + t];
    if (t < DN) xrow[t] = x[(size_t)n * DN + t];
    __syncthreads();

    if (t < DN) {
        float acc = deg[n] * b2[t];
#pragma unroll 16
        for (int j = 0; j < HH; ++j) acc = fmaf(hrow[j], W2[(size_t)j * DN + t], acc);
        aggs[t] = acc;
    }
    __syncthreads();

    {
        float acc = bu1[t];
#pragma unroll 16
        for (int k = 0; k < DN; ++k) acc = fmaf(xrow[k], U1[(size_t)k * HH + t], acc);
#pragma unroll 16
        for (int k = 0; k < DN; ++k) acc = fmaf(aggs[k], U1[(size_t)(DN + k) * HH + t], acc);
        um[t] = fmaxf(acc, 0.f);
    }
    __syncthreads();

    if (t < DN) {
        float acc = bu2[t];
#pragma unroll 16
        for (int m = 0; m < HH; ++m) acc = fmaf(um[m], U2[(size_t)m * DN + t], acc);
        out[(size_t)n * DN + t] = acc;
    }
}

extern "C" void kernel_launch(void* const* d_in, const int* in_sizes, int n_in,
                              void* d_out, int out_size, void* d_ws, size_t ws_size,
                              hipStream_t stream) {
    const float* x   = (const float*)d_in[0];
    const int*   ei  = (const int*)d_in[1];
    const float* ef  = (const float*)d_in[2];
    const float* W1  = (const float*)d_in[3];
    const float* b1  = (const float*)d_in[4];
    const float* W2  = (const float*)d_in[5];
    const float* b2  = (const float*)d_in[6];
    const float* U1  = (const float*)d_in[7];
    const float* bu1 = (const float*)d_in[8];
    const float* U2  = (const float*)d_in[9];
    const float* bu2 = (const float*)d_in[10];
    float* out = (float*)d_out;

    float* XA   = (float*)d_ws;                  // [NN,128]
    float* XB   = XA + (size_t)NN * HH;          // [NN,128]
    float* Hagg = XB + (size_t)NN * HH;          // [NN,128]
    float* deg  = Hagg + (size_t)NN * HH;        // [NN]

    // Zero the accumulators (Hagg and deg are contiguous).
    hipMemsetAsync(Hagg, 0, ((size_t)NN * HH + NN) * sizeof(float), stream);

    k_xproj<<<NN, 256, 0, stream>>>(x, W1, XA, XB);
    k_edge<<<NE / 4, 256, 0, stream>>>(ei, ef, W1, b1, XA, XB, Hagg, deg);
    k_update<<<NN, 128, 0, stream>>>(x, Hagg, deg, W2, b2, U1, bu1, U2, bu2, out);
}

// Round 2
// 757.018 us; speedup vs baseline: 1.3787x; 1.3787x over previous
//
#include <hip/hip_runtime.h>
#include <math.h>

#define NN 100000       // N_NODES
#define NE 800000       // N_EDGES
#define DN 64           // D_NODE
#define DE 4            // D_EDGE
#define HH 128          // H_MSG == H_UPD
#define NT 64           // nodes per block (tiled node GEMMs)

// ---------------------------------------------------------------------------
// Kernel 1: XA = x @ W1[0:64,:], XB = x @ W1[64:128,:]
// 64 nodes/block, 256 threads, 8 nodes x 8 cols per thread (cols over [XA|XB]).
// Weights read once per block (L2 traffic 64KB * 1563 blocks = 100 MB).
// ---------------------------------------------------------------------------
__global__ __launch_bounds__(256) void k_xproj(const float* __restrict__ x,
                                               const float* __restrict__ W1,
                                               float* __restrict__ XA,
                                               float* __restrict__ XB) {
    __shared__ float xsT[DN][NT];            // k-major x tile, 16 KB
    const int n0 = blockIdx.x * NT;
    const int t  = threadIdx.x;

    // fill xsT: thread -> node i = t&63, k-range (t>>6)*16
    {
        const int i  = t & 63;
        const int k0 = (t >> 6) * 16;
        const int n  = n0 + i;
        if (n < NN) {
            const float4* src = (const float4*)(x + (size_t)n * DN + k0);
#pragma unroll
            for (int q = 0; q < 4; ++q) {
                float4 v = src[q];
                xsT[k0 + q * 4 + 0][i] = v.x;
                xsT[k0 + q * 4 + 1][i] = v.y;
                xsT[k0 + q * 4 + 2][i] = v.z;
                xsT[k0 + q * 4 + 3][i] = v.w;
            }
        } else {
#pragma unroll
            for (int q = 0; q < 16; ++q) xsT[k0 + q][i] = 0.f;
        }
    }
    __syncthreads();

    const int cg = t & 31;        // 32 col-groups * 8 cols = 256 combined cols
    const int ng = t >> 5;        // 8 node-groups * 8 nodes
    const int c0 = cg * 8;
    // combined col c<128 -> W1[k][c] (XA); c>=128 -> W1[64+k][c-128] (XB)
    const float* wbase = (c0 < HH) ? (W1 + c0) : (W1 + (size_t)DN * HH + (c0 - HH));

    float acc[8][8];
#pragma unroll
    for (int i = 0; i < 8; ++i)
#pragma unroll
        for (int c = 0; c < 8; ++c) acc[i][c] = 0.f;

#pragma unroll 2
    for (int k = 0; k < DN; ++k) {
        float4 xa = *(const float4*)&xsT[k][ng * 8];
        float4 xb = *(const float4*)&xsT[k][ng * 8 + 4];
        float4 w0 = *(const float4*)(wbase + (size_t)k * HH);
        float4 w1 = *(const float4*)(wbase + (size_t)k * HH + 4);
        const float xi[8] = {xa.x, xa.y, xa.z, xa.w, xb.x, xb.y, xb.z, xb.w};
        const float wc[8] = {w0.x, w0.y, w0.z, w0.w, w1.x, w1.y, w1.z, w1.w};
#pragma unroll
        for (int i = 0; i < 8; ++i)
#pragma unroll
            for (int c = 0; c < 8; ++c) acc[i][c] = fmaf(xi[i], wc[c], acc[i][c]);
    }

    float* obase = (c0 < HH) ? (XA + c0) : (XB + (c0 - HH));
#pragma unroll
    for (int i = 0; i < 8; ++i) {
        const int n = n0 + ng * 8 + i;
        if (n < NN) {
            float* dst = obase + (size_t)n * HH;
            *(float4*)(dst)     = make_float4(acc[i][0], acc[i][1], acc[i][2], acc[i][3]);
            *(float4*)(dst + 4) = make_float4(acc[i][4], acc[i][5], acc[i][6], acc[i][7]);
        }
    }
}

// ---------------------------------------------------------------------------
// Kernel 2: per-edge hidden + scatter-add (unchanged this round).
// ---------------------------------------------------------------------------
__global__ __launch_bounds__(256) void k_edge(const int* __restrict__ ei,
                                              const float* __restrict__ ef,
                                              const float* __restrict__ W1,
                                              const float* __restrict__ b1,
                                              const float* __restrict__ XA,
                                              const float* __restrict__ XB,
                                              float* __restrict__ Hagg,
                                              float* __restrict__ deg) {
    const int wave = threadIdx.x >> 6;
    const int lane = threadIdx.x & 63;
    const long e = (long)blockIdx.x * 4 + wave;
    if (e >= NE) return;
    const int s = ei[e];
    const int d = ei[NE + e];

    float t = 0.f;
    if (lane < DE) t = log1pf(ef[e * DE + lane]);
    const float l0 = __shfl(t, 0);
    const float l1 = __shfl(t, 1);
    const float l2 = __shfl(t, 2);
    const float l3 = __shfl(t, 3);

    const float* we = W1 + 128 * HH;   // W1[128:132,:]
    const size_t sb = (size_t)s * HH;
    const size_t db = (size_t)d * HH;
#pragma unroll
    for (int r = 0; r < 2; ++r) {
        const int j = lane + r * 64;
        float h = XA[sb + j] + XB[db + j] + b1[j];
        h = fmaf(l0, we[0 * HH + j], h);
        h = fmaf(l1, we[1 * HH + j], h);
        h = fmaf(l2, we[2 * HH + j], h);
        h = fmaf(l3, we[3 * HH + j], h);
        h = fmaxf(h, 0.f);
        atomicAdd(&Hagg[db + j], h);
    }
    if (lane == 0) atomicAdd(&deg[d], 1.f);
}

// ---------------------------------------------------------------------------
// Kernel 3: fused per-node-tile update. 64 nodes/block, 256 threads.
//   P1: agg = Hagg @ W2 + deg*b2          (K=128 -> 64)
//   P2: u   = relu([x, agg] @ U1 + bu1)   (K=128 -> 128)
//   P3: out = u @ U2 + bu2                (K=128 -> 64)
// LDS: xaggT[128][64] (x rows 0-63, agg rows 64-127) + bufT[128][64]
// (Hagg^T, reused as u^T) = exactly 64 KB.
// ---------------------------------------------------------------------------
__global__ __launch_bounds__(256) void k_update(const float* __restrict__ x,
                                                const float* __restrict__ Hagg,
                                                const float* __restrict__ deg,
                                                const float* __restrict__ W2,
                                                const float* __restrict__ b2,
                                                const float* __restrict__ U1,
                                                const float* __restrict__ bu1,
                                                const float* __restrict__ U2,
                                                const float* __restrict__ bu2,
                                                float* __restrict__ out) {
    __shared__ float xaggT[2 * DN][NT];   // 32 KB
    __shared__ float bufT[HH][NT];        // 32 KB
    const int n0 = blockIdx.x * NT;
    const int t  = threadIdx.x;

    // P0a: stage x^T (rows 0-63 of xaggT)
    {
        const int i  = t & 63;
        const int k0 = (t >> 6) * 16;
        const int n  = n0 + i;
        if (n < NN) {
            const float4* src = (const float4*)(x + (size_t)n * DN + k0);
#pragma unroll
            for (int q = 0; q < 4; ++q) {
                float4 v = src[q];
                xaggT[k0 + q * 4 + 0][i] = v.x;
                xaggT[k0 + q * 4 + 1][i] = v.y;
                xaggT[k0 + q * 4 + 2][i] = v.z;
                xaggT[k0 + q * 4 + 3][i] = v.w;
            }
        } else {
#pragma unroll
            for (int q = 0; q < 16; ++q) xaggT[k0 + q][i] = 0.f;
        }
    }
    // P0b: stage Hagg^T into bufT
    {
        const int i  = t & 63;
        const int k0 = (t >> 6) * 32;
        const int n  = n0 + i;
        if (n < NN) {
            const float4* src = (const float4*)(Hagg + (size_t)n * HH + k0);
#pragma unroll
            for (int q = 0; q < 8; ++q) {
                float4 v = src[q];
                bufT[k0 + q * 4 + 0][i] = v.x;
                bufT[k0 + q * 4 + 1][i] = v.y;
                bufT[k0 + q * 4 + 2][i] = v.z;
                bufT[k0 + q * 4 + 3][i] = v.w;
            }
        } else {
#pragma unroll
            for (int q = 0; q < 32; ++q) bufT[k0 + q][i] = 0.f;
        }
    }
    __syncthreads();

    // ---- P1: agg = Hagg @ W2 + deg*b2 -> xaggT rows 64-127 ----
    {
        const int ng = t & 15;   // 16 groups * 4 nodes
        const int cg = t >> 4;   // 16 groups * 4 cols
        float dg[4], bb[4];
#pragma unroll
        for (int i = 0; i < 4; ++i) {
            const int n = n0 + ng * 4 + i;
            dg[i] = (n < NN) ? deg[n] : 0.f;
        }
#pragma unroll
        for (int c = 0; c < 4; ++c) bb[c] = b2[cg * 4 + c];
        float acc[4][4];
#pragma unroll
        for (int i = 0; i < 4; ++i)
#pragma unroll
            for (int c = 0; c < 4; ++c) acc[i][c] = dg[i] * bb[c];

#pragma unroll 2
        for (int k = 0; k < HH; ++k) {
            float4 h = *(const float4*)&bufT[k][ng * 4];
            float4 w = *(const float4*)(W2 + (size_t)k * DN + cg * 4);
            const float hi[4] = {h.x, h.y, h.z, h.w};
            const float wc[4] = {w.x, w.y, w.z, w.w};
#pragma unroll
            for (int i = 0; i < 4; ++i)
#pragma unroll
                for (int c = 0; c < 4; ++c) acc[i][c] = fmaf(hi[i], wc[c], acc[i][c]);
        }
        // store agg^T (node-contiguous float4 per col)
#pragma unroll
        for (int c = 0; c < 4; ++c) {
            *(float4*)&xaggT[DN + cg * 4 + c][ng * 4] =
                make_float4(acc[0][c], acc[1][c], acc[2][c], acc[3][c]);
        }
    }
    __syncthreads();

    // ---- P2: u = relu([x,agg] @ U1 + bu1) -> bufT (u^T) ----
    {
        const int ng = t & 7;    // 8 groups * 8 nodes
        const int cg = t >> 3;   // 32 groups * 4 cols
        float acc[8][4];
        float bb[4];
#pragma unroll
        for (int c = 0; c < 4; ++c) bb[c] = bu1[cg * 4 + c];
#pragma unroll
        for (int i = 0; i < 8; ++i)
#pragma unroll
            for (int c = 0; c < 4; ++c) acc[i][c] = bb[c];

#pragma unroll 2
        for (int k = 0; k < 2 * DN; ++k) {
            float4 a0 = *(const float4*)&xaggT[k][ng * 8];
            float4 a1 = *(const float4*)&xaggT[k][ng * 8 + 4];
            float4 w  = *(const float4*)(U1 + (size_t)k * HH + cg * 4);
            const float ai[8] = {a0.x, a0.y, a0.z, a0.w, a1.x, a1.y, a1.z, a1.w};
            const float wc[4] = {w.x, w.y, w.z, w.w};
#pragma unroll
            for (int i = 0; i < 8; ++i)
#pragma unroll
                for (int c = 0; c < 4; ++c) acc[i][c] = fmaf(ai[i], wc[c], acc[i][c]);
        }
        __syncthreads();   // bufT (Hagg^T) fully consumed in P1; safe to overwrite
#pragma unroll
        for (int c = 0; c < 4; ++c) {
            *(float4*)&bufT[cg * 4 + c][ng * 8] =
                make_float4(fmaxf(acc[0][c], 0.f), fmaxf(acc[1][c], 0.f),
                            fmaxf(acc[2][c], 0.f), fmaxf(acc[3][c], 0.f));
            *(float4*)&bufT[cg * 4 + c][ng * 8 + 4] =
                make_float4(fmaxf(acc[4][c], 0.f), fmaxf(acc[5][c], 0.f),
                            fmaxf(acc[6][c], 0.f), fmaxf(acc[7][c], 0.f));
        }
    }
    __syncthreads();

    // ---- P3: out = u @ U2 + bu2 ----
    {
        const int cg = t & 15;   // 16 groups * 4 cols (fast dim -> coalesced store)
        const int ng = t >> 4;   // 16 groups * 4 nodes
        float acc[4][4];
        float bb[4];
#pragma unroll
        for (int c = 0; c < 4; ++c) bb[c] = bu2[cg * 4 + c];
#pragma unroll
        for (int i = 0; i < 4; ++i)
#pragma unroll
            for (int c = 0; c < 4; ++c) acc[i][c] = bb[c];

#pragma unroll 2
        for (int k = 0; k < HH; ++k) {
            float4 u = *(const float4*)&bufT[k][ng * 4];
            float4 w = *(const float4*)(U2 + (size_t)k * DN + cg * 4);
            const float ui[4] = {u.x, u.y, u.z, u.w};
            const float wc[4] = {w.x, w.y, w.z, w.w};
#pragma unroll
            for (int i = 0; i < 4; ++i)
#pragma unroll
                for (int c = 0; c < 4; ++c) acc[i][c] = fmaf(ui[i], wc[c], acc[i][c]);
        }
#pragma unroll
        for (int i = 0; i < 4; ++i) {
            const int n = n0 + ng * 4 + i;
            if (n < NN) {
                *(float4*)(out + (size_t)n * DN + cg * 4) =
                    make_float4(acc[i][0], acc[i][1], acc[i][2], acc[i][3]);
            }
        }
    }
}

extern "C" void kernel_launch(void* const* d_in, const int* in_sizes, int n_in,
                              void* d_out, int out_size, void* d_ws, size_t ws_size,
                              hipStream_t stream) {
    const float* x   = (const float*)d_in[0];
    const int*   ei  = (const int*)d_in[1];
    const float* ef  = (const float*)d_in[2];
    const float* W1  = (const float*)d_in[3];
    const float* b1  = (const float*)d_in[4];
    const float* W2  = (const float*)d_in[5];
    const float* b2  = (const float*)d_in[6];
    const float* U1  = (const float*)d_in[7];
    const float* bu1 = (const float*)d_in[8];
    const float* U2  = (const float*)d_in[9];
    const float* bu2 = (const float*)d_in[10];
    float* out = (float*)d_out;

    float* XA   = (float*)d_ws;                  // [NN,128]
    float* XB   = XA + (size_t)NN * HH;          // [NN,128]
    float* Hagg = XB + (size_t)NN * HH;          // [NN,128]
    float* deg  = Hagg + (size_t)NN * HH;        // [NN]

    hipMemsetAsync(Hagg, 0, ((size_t)NN * HH + NN) * sizeof(float), stream);

    const int nblk = (NN + NT - 1) / NT;
    k_xproj<<<nblk, 256, 0, stream>>>(x, W1, XA, XB);
    k_edge<<<NE / 4, 256, 0, stream>>>(ei, ef, W1, b1, XA, XB, Hagg, deg);
    k_update<<<nblk, 256, 0, stream>>>(x, Hagg, deg, W2, b2, U1, bu1, U2, bu2, out);
}

// Round 3
// 577.274 us; speedup vs baseline: 1.8080x; 1.3114x over previous
//
#include <hip/hip_runtime.h>
#include <math.h>

#define NN 100000       // N_NODES
#define NE 800000       // N_EDGES
#define DN 64           // D_NODE
#define DE 4            // D_EDGE
#define HH 128          // H_MSG == H_UPD
#define NT 64           // nodes per block (tiled node GEMMs)
#define SCAN_B 256
#define NBLK_SCAN ((NN + SCAN_B - 1) / SCAN_B)   // 391

// ---------------------------------------------------------------------------
// Kernel 1: XA = x @ W1[0:64,:], XB = x @ W1[64:128,:]  (unchanged from R2)
// ---------------------------------------------------------------------------
__global__ __launch_bounds__(256) void k_xproj(const float* __restrict__ x,
                                               const float* __restrict__ W1,
                                               float* __restrict__ XA,
                                               float* __restrict__ XB) {
    __shared__ float xsT[DN][NT];
    const int n0 = blockIdx.x * NT;
    const int t  = threadIdx.x;
    {
        const int i  = t & 63;
        const int k0 = (t >> 6) * 16;
        const int n  = n0 + i;
        if (n < NN) {
            const float4* src = (const float4*)(x + (size_t)n * DN + k0);
#pragma unroll
            for (int q = 0; q < 4; ++q) {
                float4 v = src[q];
                xsT[k0 + q * 4 + 0][i] = v.x;
                xsT[k0 + q * 4 + 1][i] = v.y;
                xsT[k0 + q * 4 + 2][i] = v.z;
                xsT[k0 + q * 4 + 3][i] = v.w;
            }
        } else {
#pragma unroll
            for (int q = 0; q < 16; ++q) xsT[k0 + q][i] = 0.f;
        }
    }
    __syncthreads();

    const int cg = t & 31;
    const int ng = t >> 5;
    const int c0 = cg * 8;
    const float* wbase = (c0 < HH) ? (W1 + c0) : (W1 + (size_t)DN * HH + (c0 - HH));

    float acc[8][8];
#pragma unroll
    for (int i = 0; i < 8; ++i)
#pragma unroll
        for (int c = 0; c < 8; ++c) acc[i][c] = 0.f;

#pragma unroll 2
    for (int k = 0; k < DN; ++k) {
        float4 xa = *(const float4*)&xsT[k][ng * 8];
        float4 xb = *(const float4*)&xsT[k][ng * 8 + 4];
        float4 w0 = *(const float4*)(wbase + (size_t)k * HH);
        float4 w1 = *(const float4*)(wbase + (size_t)k * HH + 4);
        const float xi[8] = {xa.x, xa.y, xa.z, xa.w, xb.x, xb.y, xb.z, xb.w};
        const float wc[8] = {w0.x, w0.y, w0.z, w0.w, w1.x, w1.y, w1.z, w1.w};
#pragma unroll
        for (int i = 0; i < 8; ++i)
#pragma unroll
            for (int c = 0; c < 8; ++c) acc[i][c] = fmaf(xi[i], wc[c], acc[i][c]);
    }

    float* obase = (c0 < HH) ? (XA + c0) : (XB + (c0 - HH));
#pragma unroll
    for (int i = 0; i < 8; ++i) {
        const int n = n0 + ng * 8 + i;
        if (n < NN) {
            float* dst = obase + (size_t)n * HH;
            *(float4*)(dst)     = make_float4(acc[i][0], acc[i][1], acc[i][2], acc[i][3]);
            *(float4*)(dst + 4) = make_float4(acc[i][4], acc[i][5], acc[i][6], acc[i][7]);
        }
    }
}

// ---------------------------------------------------------------------------
// Counting sort by destination
// ---------------------------------------------------------------------------
__global__ __launch_bounds__(256) void k_hist(const int* __restrict__ ei,
                                              int* __restrict__ cnt) {
    const int e = blockIdx.x * 256 + threadIdx.x;
    if (e < NE) atomicAdd(&cnt[ei[NE + e]], 1);
}

__global__ __launch_bounds__(SCAN_B) void k_scan_a(const int* __restrict__ cnt,
                                                   int* __restrict__ pos,
                                                   int* __restrict__ bsum) {
    __shared__ int sh[SCAN_B];
    const int n = blockIdx.x * SCAN_B + threadIdx.x;
    const int c = (n < NN) ? cnt[n] : 0;
    sh[threadIdx.x] = c;
    __syncthreads();
    int v = c;
#pragma unroll
    for (int off = 1; off < SCAN_B; off <<= 1) {
        int add = (threadIdx.x >= off) ? sh[threadIdx.x - off] : 0;
        __syncthreads();
        v += add;
        sh[threadIdx.x] = v;
        __syncthreads();
    }
    if (n < NN) pos[n] = v - c;                         // exclusive within block
    if (threadIdx.x == SCAN_B - 1) bsum[blockIdx.x] = v; // block total
}

__global__ __launch_bounds__(512) void k_scan_b(int* __restrict__ bsum) {
    __shared__ int sh[512];
    const int i = threadIdx.x;
    const int c = (i < NBLK_SCAN) ? bsum[i] : 0;
    sh[i] = c;
    __syncthreads();
    int v = c;
#pragma unroll
    for (int off = 1; off < 512; off <<= 1) {
        int add = (i >= off) ? sh[i - off] : 0;
        __syncthreads();
        v += add;
        sh[i] = v;
        __syncthreads();
    }
    if (i < NBLK_SCAN) bsum[i] = v - c;                  // exclusive, in place
}

__global__ __launch_bounds__(256) void k_scatter(const int* __restrict__ ei,
                                                 const float* __restrict__ ef,
                                                 int* __restrict__ pos,
                                                 const int* __restrict__ boff,
                                                 int* __restrict__ es,
                                                 float4* __restrict__ ef4) {
    const int e = blockIdx.x * 256 + threadIdx.x;
    if (e >= NE) return;
    const int s = ei[e];
    const int d = ei[NE + e];
    const int slot = atomicAdd(&pos[d], 1) + boff[d >> 8];
    es[slot] = s;
    ef4[slot] = make_float4(log1pf(ef[e * 4 + 0]), log1pf(ef[e * 4 + 1]),
                            log1pf(ef[e * 4 + 2]), log1pf(ef[e * 4 + 3]));
}

// ---------------------------------------------------------------------------
// Segmented reduce: one wave per destination node. No atomics.
//   Hagg[d] = sum_e relu(XA[s_e] + XB[d] + b1 + l_e @ W1[128:132,:])
// ---------------------------------------------------------------------------
__global__ __launch_bounds__(256) void k_agg(const int* __restrict__ es,
                                             const float4* __restrict__ ef4,
                                             const int* __restrict__ pos,
                                             const int* __restrict__ boff,
                                             const int* __restrict__ cnt,
                                             const float* __restrict__ XA,
                                             const float* __restrict__ XB,
                                             const float* __restrict__ W1,
                                             const float* __restrict__ b1,
                                             float* __restrict__ Hagg,
                                             float* __restrict__ deg) {
    const int wave = threadIdx.x >> 6;
    const int lane = threadIdx.x & 63;
    const int d = blockIdx.x * 4 + wave;
    if (d >= NN) return;
    const int c     = cnt[d];
    const int end   = pos[d] + boff[d >> 8];   // pos was advanced to segment end
    const int start = end - c;

    const float* we = W1 + 128 * HH;
    const float base0 = XB[(size_t)d * HH + lane]      + b1[lane];
    const float base1 = XB[(size_t)d * HH + 64 + lane] + b1[64 + lane];
    const float w00 = we[0 * HH + lane],      w10 = we[1 * HH + lane];
    const float w20 = we[2 * HH + lane],      w30 = we[3 * HH + lane];
    const float w01 = we[0 * HH + 64 + lane], w11 = we[1 * HH + 64 + lane];
    const float w21 = we[2 * HH + 64 + lane], w31 = we[3 * HH + 64 + lane];

    float acc0 = 0.f, acc1 = 0.f;
    for (int k = start; k < end; ++k) {
        const int s = es[k];
        const float4 f = ef4[k];
        const float* xr = XA + (size_t)s * HH;
        float h0 = xr[lane]      + base0;
        float h1 = xr[64 + lane] + base1;
        h0 = fmaf(f.x, w00, h0); h0 = fmaf(f.y, w10, h0);
        h0 = fmaf(f.z, w20, h0); h0 = fmaf(f.w, w30, h0);
        h1 = fmaf(f.x, w01, h1); h1 = fmaf(f.y, w11, h1);
        h1 = fmaf(f.z, w21, h1); h1 = fmaf(f.w, w31, h1);
        acc0 += fmaxf(h0, 0.f);
        acc1 += fmaxf(h1, 0.f);
    }
    Hagg[(size_t)d * HH + lane]      = acc0;
    Hagg[(size_t)d * HH + 64 + lane] = acc1;
    if (lane == 0) deg[d] = (float)c;
}

// ---------------------------------------------------------------------------
// Fallback edge kernel (atomic path) — used only if ws_size is too small.
// ---------------------------------------------------------------------------
__global__ __launch_bounds__(256) void k_edge_atomic(const int* __restrict__ ei,
                                                     const float* __restrict__ ef,
                                                     const float* __restrict__ W1,
                                                     const float* __restrict__ b1,
                                                     const float* __restrict__ XA,
                                                     const float* __restrict__ XB,
                                                     float* __restrict__ Hagg,
                                                     float* __restrict__ deg) {
    const int wave = threadIdx.x >> 6;
    const int lane = threadIdx.x & 63;
    const long e = (long)blockIdx.x * 4 + wave;
    if (e >= NE) return;
    const int s = ei[e];
    const int d = ei[NE + e];

    float t = 0.f;
    if (lane < DE) t = log1pf(ef[e * DE + lane]);
    const float l0 = __shfl(t, 0);
    const float l1 = __shfl(t, 1);
    const float l2 = __shfl(t, 2);
    const float l3 = __shfl(t, 3);

    const float* we = W1 + 128 * HH;
    const size_t sb = (size_t)s * HH;
    const size_t db = (size_t)d * HH;
#pragma unroll
    for (int r = 0; r < 2; ++r) {
        const int j = lane + r * 64;
        float h = XA[sb + j] + XB[db + j] + b1[j];
        h = fmaf(l0, we[0 * HH + j], h);
        h = fmaf(l1, we[1 * HH + j], h);
        h = fmaf(l2, we[2 * HH + j], h);
        h = fmaf(l3, we[3 * HH + j], h);
        h = fmaxf(h, 0.f);
        atomicAdd(&Hagg[db + j], h);
    }
    if (lane == 0) atomicAdd(&deg[d], 1.f);
}

// ---------------------------------------------------------------------------
// Kernel 3: fused per-node-tile update (unchanged from R2).
// ---------------------------------------------------------------------------
__global__ __launch_bounds__(256) void k_update(const float* __restrict__ x,
                                                const float* __restrict__ Hagg,
                                                const float* __restrict__ deg,
                                                const float* __restrict__ W2,
                                                const float* __restrict__ b2,
                                                const float* __restrict__ U1,
                                                const float* __restrict__ bu1,
                                                const float* __restrict__ U2,
                                                const float* __restrict__ bu2,
                                                float* __restrict__ out) {
    __shared__ float xaggT[2 * DN][NT];
    __shared__ float bufT[HH][NT];
    const int n0 = blockIdx.x * NT;
    const int t  = threadIdx.x;

    {
        const int i  = t & 63;
        const int k0 = (t >> 6) * 16;
        const int n  = n0 + i;
        if (n < NN) {
            const float4* src = (const float4*)(x + (size_t)n * DN + k0);
#pragma unroll
            for (int q = 0; q < 4; ++q) {
                float4 v = src[q];
                xaggT[k0 + q * 4 + 0][i] = v.x;
                xaggT[k0 + q * 4 + 1][i] = v.y;
                xaggT[k0 + q * 4 + 2][i] = v.z;
                xaggT[k0 + q * 4 + 3][i] = v.w;
            }
        } else {
#pragma unroll
            for (int q = 0; q < 16; ++q) xaggT[k0 + q][i] = 0.f;
        }
    }
    {
        const int i  = t & 63;
        const int k0 = (t >> 6) * 32;
        const int n  = n0 + i;
        if (n < NN) {
            const float4* src = (const float4*)(Hagg + (size_t)n * HH + k0);
#pragma unroll
            for (int q = 0; q < 8; ++q) {
                float4 v = src[q];
                bufT[k0 + q * 4 + 0][i] = v.x;
                bufT[k0 + q * 4 + 1][i] = v.y;
                bufT[k0 + q * 4 + 2][i] = v.z;
                bufT[k0 + q * 4 + 3][i] = v.w;
            }
        } else {
#pragma unroll
            for (int q = 0; q < 32; ++q) bufT[k0 + q][i] = 0.f;
        }
    }
    __syncthreads();

    {
        const int ng = t & 15;
        const int cg = t >> 4;
        float dg[4], bb[4];
#pragma unroll
        for (int i = 0; i < 4; ++i) {
            const int n = n0 + ng * 4 + i;
            dg[i] = (n < NN) ? deg[n] : 0.f;
        }
#pragma unroll
        for (int c = 0; c < 4; ++c) bb[c] = b2[cg * 4 + c];
        float acc[4][4];
#pragma unroll
        for (int i = 0; i < 4; ++i)
#pragma unroll
            for (int c = 0; c < 4; ++c) acc[i][c] = dg[i] * bb[c];

#pragma unroll 2
        for (int k = 0; k < HH; ++k) {
            float4 h = *(const float4*)&bufT[k][ng * 4];
            float4 w = *(const float4*)(W2 + (size_t)k * DN + cg * 4);
            const float hi[4] = {h.x, h.y, h.z, h.w};
            const float wc[4] = {w.x, w.y, w.z, w.w};
#pragma unroll
            for (int i = 0; i < 4; ++i)
#pragma unroll
                for (int c = 0; c < 4; ++c) acc[i][c] = fmaf(hi[i], wc[c], acc[i][c]);
        }
#pragma unroll
        for (int c = 0; c < 4; ++c) {
            *(float4*)&xaggT[DN + cg * 4 + c][ng * 4] =
                make_float4(acc[0][c], acc[1][c], acc[2][c], acc[3][c]);
        }
    }
    __syncthreads();

    {
        const int ng = t & 7;
        const int cg = t >> 3;
        float acc[8][4];
        float bb[4];
#pragma unroll
        for (int c = 0; c < 4; ++c) bb[c] = bu1[cg * 4 + c];
#pragma unroll
        for (int i = 0; i < 8; ++i)
#pragma unroll
            for (int c = 0; c < 4; ++c) acc[i][c] = bb[c];

#pragma unroll 2
        for (int k = 0; k < 2 * DN; ++k) {
            float4 a0 = *(const float4*)&xaggT[k][ng * 8];
            float4 a1 = *(const float4*)&xaggT[k][ng * 8 + 4];
            float4 w  = *(const float4*)(U1 + (size_t)k * HH + cg * 4);
            const float ai[8] = {a0.x, a0.y, a0.z, a0.w, a1.x, a1.y, a1.z, a1.w};
            const float wc[4] = {w.x, w.y, w.z, w.w};
#pragma unroll
            for (int i = 0; i < 8; ++i)
#pragma unroll
                for (int c = 0; c < 4; ++c) acc[i][c] = fmaf(ai[i], wc[c], acc[i][c]);
        }
        __syncthreads();
#pragma unroll
        for (int c = 0; c < 4; ++c) {
            *(float4*)&bufT[cg * 4 + c][ng * 8] =
                make_float4(fmaxf(acc[0][c], 0.f), fmaxf(acc[1][c], 0.f),
                            fmaxf(acc[2][c], 0.f), fmaxf(acc[3][c], 0.f));
            *(float4*)&bufT[cg * 4 + c][ng * 8 + 4] =
                make_float4(fmaxf(acc[4][c], 0.f), fmaxf(acc[5][c], 0.f),
                            fmaxf(acc[6][c], 0.f), fmaxf(acc[7][c], 0.f));
        }
    }
    __syncthreads();

    {
        const int cg = t & 15;
        const int ng = t >> 4;
        float acc[4][4];
        float bb[4];
#pragma unroll
        for (int c = 0; c < 4; ++c) bb[c] = bu2[cg * 4 + c];
#pragma unroll
        for (int i = 0; i < 4; ++i)
#pragma unroll
            for (int c = 0; c < 4; ++c) acc[i][c] = bb[c];

#pragma unroll 2
        for (int k = 0; k < HH; ++k) {
            float4 u = *(const float4*)&bufT[k][ng * 4];
            float4 w = *(const float4*)(U2 + (size_t)k * DN + cg * 4);
            const float ui[4] = {u.x, u.y, u.z, u.w};
            const float wc[4] = {w.x, w.y, w.z, w.w};
#pragma unroll
            for (int i = 0; i < 4; ++i)
#pragma unroll
                for (int c = 0; c < 4; ++c) acc[i][c] = fmaf(ui[i], wc[c], acc[i][c]);
        }
#pragma unroll
        for (int i = 0; i < 4; ++i) {
            const int n = n0 + ng * 4 + i;
            if (n < NN) {
                *(float4*)(out + (size_t)n * DN + cg * 4) =
                    make_float4(acc[i][0], acc[i][1], acc[i][2], acc[i][3]);
            }
        }
    }
}

extern "C" void kernel_launch(void* const* d_in, const int* in_sizes, int n_in,
                              void* d_out, int out_size, void* d_ws, size_t ws_size,
                              hipStream_t stream) {
    const float* x   = (const float*)d_in[0];
    const int*   ei  = (const int*)d_in[1];
    const float* ef  = (const float*)d_in[2];
    const float* W1  = (const float*)d_in[3];
    const float* b1  = (const float*)d_in[4];
    const float* W2  = (const float*)d_in[5];
    const float* b2  = (const float*)d_in[6];
    const float* U1  = (const float*)d_in[7];
    const float* bu1 = (const float*)d_in[8];
    const float* U2  = (const float*)d_in[9];
    const float* bu2 = (const float*)d_in[10];
    float* out = (float*)d_out;

    // workspace layout
    float* XA   = (float*)d_ws;                        // [NN,128] 51.2 MB
    float* XB   = XA + (size_t)NN * HH;                // [NN,128] 51.2 MB
    float* Hagg = XB + (size_t)NN * HH;                // [NN,128] 51.2 MB
    float* deg  = Hagg + (size_t)NN * HH;              // [NN]
    int*   cnt  = (int*)(deg + NN);                    // [NN]
    int*   pos  = cnt + NN;                            // [NN]
    int*   boff = pos + NN;                            // [1024]
    int*   es   = boff + 1024;                         // [NE]
    float4* ef4 = (float4*)(es + NE);                  // [NE] 16B each (16B aligned: offset is multiple of 16)
    const size_t need = (size_t)((char*)(ef4 + NE) - (char*)d_ws);

    const int nblk = (NN + NT - 1) / NT;

    if (ws_size >= need) {
        // sort-based path: no float atomics
        hipMemsetAsync(cnt, 0, (size_t)NN * sizeof(int), stream);
        k_xproj<<<nblk, 256, 0, stream>>>(x, W1, XA, XB);
        k_hist<<<(NE + 255) / 256, 256, 0, stream>>>(ei, cnt);
        k_scan_a<<<NBLK_SCAN, SCAN_B, 0, stream>>>(cnt, pos, boff);
        k_scan_b<<<1, 512, 0, stream>>>(boff);
        k_scatter<<<(NE + 255) / 256, 256, 0, stream>>>(ei, ef, pos, boff, es, ef4);
        k_agg<<<(NN + 3) / 4, 256, 0, stream>>>(es, ef4, pos, boff, cnt, XA, XB, W1, b1, Hagg, deg);
    } else {
        // fallback: atomic scatter-add path (R2 behavior)
        hipMemsetAsync(Hagg, 0, ((size_t)NN * HH + NN) * sizeof(float), stream);
        k_xproj<<<nblk, 256, 0, stream>>>(x, W1, XA, XB);
        k_edge_atomic<<<NE / 4, 256, 0, stream>>>(ei, ef, W1, b1, XA, XB, Hagg, deg);
    }
    k_update<<<nblk, 256, 0, stream>>>(x, Hagg, deg, W2, b2, U1, bu1, U2, bu2, out);
}

// Round 4
// 516.284 us; speedup vs baseline: 2.0216x; 1.1181x over previous
//
#include <hip/hip_runtime.h>
#include <math.h>

#define NN 100000       // N_NODES
#define NE 800000       // N_EDGES
#define DN 64           // D_NODE
#define DE 4            // D_EDGE
#define HH 128          // H_MSG == H_UPD
#define NT 64           // nodes per block (k_xproj)
#define NT2 32          // nodes per block (k_update) — 32 KB LDS, ~5 blocks/CU
#define SCAN_B 256
#define NBLK_SCAN ((NN + SCAN_B - 1) / SCAN_B)   // 391

// ---------------------------------------------------------------------------
// Kernel 1: XA = x @ W1[0:64,:], XB = x @ W1[64:128,:]  (unchanged)
// ---------------------------------------------------------------------------
__global__ __launch_bounds__(256) void k_xproj(const float* __restrict__ x,
                                               const float* __restrict__ W1,
                                               float* __restrict__ XA,
                                               float* __restrict__ XB) {
    __shared__ float xsT[DN][NT];
    const int n0 = blockIdx.x * NT;
    const int t  = threadIdx.x;
    {
        const int i  = t & 63;
        const int k0 = (t >> 6) * 16;
        const int n  = n0 + i;
        if (n < NN) {
            const float4* src = (const float4*)(x + (size_t)n * DN + k0);
#pragma unroll
            for (int q = 0; q < 4; ++q) {
                float4 v = src[q];
                xsT[k0 + q * 4 + 0][i] = v.x;
                xsT[k0 + q * 4 + 1][i] = v.y;
                xsT[k0 + q * 4 + 2][i] = v.z;
                xsT[k0 + q * 4 + 3][i] = v.w;
            }
        } else {
#pragma unroll
            for (int q = 0; q < 16; ++q) xsT[k0 + q][i] = 0.f;
        }
    }
    __syncthreads();

    const int cg = t & 31;
    const int ng = t >> 5;
    const int c0 = cg * 8;
    const float* wbase = (c0 < HH) ? (W1 + c0) : (W1 + (size_t)DN * HH + (c0 - HH));

    float acc[8][8];
#pragma unroll
    for (int i = 0; i < 8; ++i)
#pragma unroll
        for (int c = 0; c < 8; ++c) acc[i][c] = 0.f;

#pragma unroll 2
    for (int k = 0; k < DN; ++k) {
        float4 xa = *(const float4*)&xsT[k][ng * 8];
        float4 xb = *(const float4*)&xsT[k][ng * 8 + 4];
        float4 w0 = *(const float4*)(wbase + (size_t)k * HH);
        float4 w1 = *(const float4*)(wbase + (size_t)k * HH + 4);
        const float xi[8] = {xa.x, xa.y, xa.z, xa.w, xb.x, xb.y, xb.z, xb.w};
        const float wc[8] = {w0.x, w0.y, w0.z, w0.w, w1.x, w1.y, w1.z, w1.w};
#pragma unroll
        for (int i = 0; i < 8; ++i)
#pragma unroll
            for (int c = 0; c < 8; ++c) acc[i][c] = fmaf(xi[i], wc[c], acc[i][c]);
    }

    float* obase = (c0 < HH) ? (XA + c0) : (XB + (c0 - HH));
#pragma unroll
    for (int i = 0; i < 8; ++i) {
        const int n = n0 + ng * 8 + i;
        if (n < NN) {
            float* dst = obase + (size_t)n * HH;
            *(float4*)(dst)     = make_float4(acc[i][0], acc[i][1], acc[i][2], acc[i][3]);
            *(float4*)(dst + 4) = make_float4(acc[i][4], acc[i][5], acc[i][6], acc[i][7]);
        }
    }
}

// ---------------------------------------------------------------------------
// Counting sort by destination (unchanged)
// ---------------------------------------------------------------------------
__global__ __launch_bounds__(256) void k_hist(const int* __restrict__ ei,
                                              int* __restrict__ cnt) {
    const int e = blockIdx.x * 256 + threadIdx.x;
    if (e < NE) atomicAdd(&cnt[ei[NE + e]], 1);
}

__global__ __launch_bounds__(SCAN_B) void k_scan_a(const int* __restrict__ cnt,
                                                   int* __restrict__ pos,
                                                   int* __restrict__ bsum) {
    __shared__ int sh[SCAN_B];
    const int n = blockIdx.x * SCAN_B + threadIdx.x;
    const int c = (n < NN) ? cnt[n] : 0;
    sh[threadIdx.x] = c;
    __syncthreads();
    int v = c;
#pragma unroll
    for (int off = 1; off < SCAN_B; off <<= 1) {
        int add = (threadIdx.x >= off) ? sh[threadIdx.x - off] : 0;
        __syncthreads();
        v += add;
        sh[threadIdx.x] = v;
        __syncthreads();
    }
    if (n < NN) pos[n] = v - c;
    if (threadIdx.x == SCAN_B - 1) bsum[blockIdx.x] = v;
}

__global__ __launch_bounds__(512) void k_scan_b(int* __restrict__ bsum) {
    __shared__ int sh[512];
    const int i = threadIdx.x;
    const int c = (i < NBLK_SCAN) ? bsum[i] : 0;
    sh[i] = c;
    __syncthreads();
    int v = c;
#pragma unroll
    for (int off = 1; off < 512; off <<= 1) {
        int add = (i >= off) ? sh[i - off] : 0;
        __syncthreads();
        v += add;
        sh[i] = v;
        __syncthreads();
    }
    if (i < NBLK_SCAN) bsum[i] = v - c;
}

__global__ __launch_bounds__(256) void k_scatter(const int* __restrict__ ei,
                                                 const float* __restrict__ ef,
                                                 int* __restrict__ pos,
                                                 const int* __restrict__ boff,
                                                 int* __restrict__ es,
                                                 float4* __restrict__ ef4) {
    const int e = blockIdx.x * 256 + threadIdx.x;
    if (e >= NE) return;
    const int s = ei[e];
    const int d = ei[NE + e];
    const int slot = atomicAdd(&pos[d], 1) + boff[d >> 8];
    es[slot] = s;
    ef4[slot] = make_float4(log1pf(ef[e * 4 + 0]), log1pf(ef[e * 4 + 1]),
                            log1pf(ef[e * 4 + 2]), log1pf(ef[e * 4 + 3]));
}

// ---------------------------------------------------------------------------
// Segmented reduce, one wave per node. Lane covers cols {2*lane, 2*lane+1}
// -> the XA gather is ONE dwordx2 per lane (full 512B row per instruction).
// 2-deep software pipeline hides the es->XA dependent-load latency.
// ---------------------------------------------------------------------------
__global__ __launch_bounds__(256) void k_agg(const int* __restrict__ es,
                                             const float4* __restrict__ ef4,
                                             const int* __restrict__ pos,
                                             const int* __restrict__ boff,
                                             const int* __restrict__ cnt,
                                             const float* __restrict__ XA,
                                             const float* __restrict__ XB,
                                             const float* __restrict__ W1,
                                             const float* __restrict__ b1,
                                             float* __restrict__ Hagg,
                                             float* __restrict__ deg) {
    const int wave = threadIdx.x >> 6;
    const int lane = threadIdx.x & 63;
    const int d = blockIdx.x * 4 + wave;
    if (d >= NN) return;
    const int c     = cnt[d];
    const int end   = pos[d] + boff[d >> 8];   // pos advanced to segment end
    const int start = end - c;
    const int j0    = lane * 2;                // cols {j0, j0+1}

    const float* we = W1 + 128 * HH;
    const float2 xb = *(const float2*)(XB + (size_t)d * HH + j0);
    const float2 bb = *(const float2*)(b1 + j0);
    const float base0 = xb.x + bb.x;
    const float base1 = xb.y + bb.y;
    const float2 wv0 = *(const float2*)(we + 0 * HH + j0);
    const float2 wv1 = *(const float2*)(we + 1 * HH + j0);
    const float2 wv2 = *(const float2*)(we + 2 * HH + j0);
    const float2 wv3 = *(const float2*)(we + 3 * HH + j0);

    float acc0 = 0.f, acc1 = 0.f;
    if (c > 0) {
        float4 f_cur = ef4[start];
        float2 a_cur = *(const float2*)(XA + (size_t)es[start] * HH + j0);
        for (int k = start; k < end; ++k) {
            const float4 f = f_cur;
            const float2 a = a_cur;
            if (k + 1 < end) {            // prefetch next edge
                const int sn = es[k + 1];
                f_cur = ef4[k + 1];
                a_cur = *(const float2*)(XA + (size_t)sn * HH + j0);
            }
            float h0 = a.x + base0;
            float h1 = a.y + base1;
            h0 = fmaf(f.x, wv0.x, h0); h0 = fmaf(f.y, wv1.x, h0);
            h0 = fmaf(f.z, wv2.x, h0); h0 = fmaf(f.w, wv3.x, h0);
            h1 = fmaf(f.x, wv0.y, h1); h1 = fmaf(f.y, wv1.y, h1);
            h1 = fmaf(f.z, wv2.y, h1); h1 = fmaf(f.w, wv3.y, h1);
            acc0 += fmaxf(h0, 0.f);
            acc1 += fmaxf(h1, 0.f);
        }
    }
    *(float2*)(Hagg + (size_t)d * HH + j0) = make_float2(acc0, acc1);
    if (lane == 0) deg[d] = (float)c;
}

// ---------------------------------------------------------------------------
// Fallback edge kernel (atomic path) — used only if ws_size is too small.
// ---------------------------------------------------------------------------
__global__ __launch_bounds__(256) void k_edge_atomic(const int* __restrict__ ei,
                                                     const float* __restrict__ ef,
                                                     const float* __restrict__ W1,
                                                     const float* __restrict__ b1,
                                                     const float* __restrict__ XA,
                                                     const float* __restrict__ XB,
                                                     float* __restrict__ Hagg,
                                                     float* __restrict__ deg) {
    const int wave = threadIdx.x >> 6;
    const int lane = threadIdx.x & 63;
    const long e = (long)blockIdx.x * 4 + wave;
    if (e >= NE) return;
    const int s = ei[e];
    const int d = ei[NE + e];

    float t = 0.f;
    if (lane < DE) t = log1pf(ef[e * DE + lane]);
    const float l0 = __shfl(t, 0);
    const float l1 = __shfl(t, 1);
    const float l2 = __shfl(t, 2);
    const float l3 = __shfl(t, 3);

    const float* we = W1 + 128 * HH;
    const size_t sb = (size_t)s * HH;
    const size_t db = (size_t)d * HH;
#pragma unroll
    for (int r = 0; r < 2; ++r) {
        const int j = lane + r * 64;
        float h = XA[sb + j] + XB[db + j] + b1[j];
        h = fmaf(l0, we[0 * HH + j], h);
        h = fmaf(l1, we[1 * HH + j], h);
        h = fmaf(l2, we[2 * HH + j], h);
        h = fmaf(l3, we[3 * HH + j], h);
        h = fmaxf(h, 0.f);
        atomicAdd(&Hagg[db + j], h);
    }
    if (lane == 0) atomicAdd(&deg[d], 1.f);
}

// ---------------------------------------------------------------------------
// Kernel 3: fused per-node-tile update, NT2=32 nodes/block, 32 KB LDS.
//   P1: agg = Hagg @ W2 + deg*b2          (K=128 -> 64)
//   P2: u   = relu([x, agg] @ U1 + bu1)   (K=128 -> 128)
//   P3: out = u @ U2 + bu2                (K=128 -> 64)
// ---------------------------------------------------------------------------
__global__ __launch_bounds__(256) void k_update(const float* __restrict__ x,
                                                const float* __restrict__ Hagg,
                                                const float* __restrict__ deg,
                                                const float* __restrict__ W2,
                                                const float* __restrict__ b2,
                                                const float* __restrict__ U1,
                                                const float* __restrict__ bu1,
                                                const float* __restrict__ U2,
                                                const float* __restrict__ bu2,
                                                float* __restrict__ out) {
    __shared__ float xaggT[2 * DN][NT2];   // 16 KB: x rows 0-63, agg rows 64-127
    __shared__ float bufT[HH][NT2];        // 16 KB: Hagg^T, reused as u^T
    const int n0 = blockIdx.x * NT2;
    const int t  = threadIdx.x;

    // stage x^T: node i = t&31, k-range (t>>5)*8 (2 float4s)
    {
        const int i  = t & 31;
        const int k0 = (t >> 5) * 8;
        const int n  = n0 + i;
        if (n < NN) {
            const float4* src = (const float4*)(x + (size_t)n * DN + k0);
#pragma unroll
            for (int q = 0; q < 2; ++q) {
                float4 v = src[q];
                xaggT[k0 + q * 4 + 0][i] = v.x;
                xaggT[k0 + q * 4 + 1][i] = v.y;
                xaggT[k0 + q * 4 + 2][i] = v.z;
                xaggT[k0 + q * 4 + 3][i] = v.w;
            }
        } else {
#pragma unroll
            for (int q = 0; q < 8; ++q) xaggT[k0 + q][i] = 0.f;
        }
    }
    // stage Hagg^T: node i = t&31, k-range (t>>5)*16 (4 float4s)
    {
        const int i  = t & 31;
        const int k0 = (t >> 5) * 16;
        const int n  = n0 + i;
        if (n < NN) {
            const float4* src = (const float4*)(Hagg + (size_t)n * HH + k0);
#pragma unroll
            for (int q = 0; q < 4; ++q) {
                float4 v = src[q];
                bufT[k0 + q * 4 + 0][i] = v.x;
                bufT[k0 + q * 4 + 1][i] = v.y;
                bufT[k0 + q * 4 + 2][i] = v.z;
                bufT[k0 + q * 4 + 3][i] = v.w;
            }
        } else {
#pragma unroll
            for (int q = 0; q < 16; ++q) bufT[k0 + q][i] = 0.f;
        }
    }
    __syncthreads();

    // ---- P1: agg = Hagg @ W2 + deg*b2 -> xaggT rows 64-127 ----
    {
        const int ng = t & 7;     // 8 groups * 4 nodes
        const int cg = t >> 3;    // 32 groups * 2 cols
        const int c0 = cg * 2;
        float dg[4];
#pragma unroll
        for (int i = 0; i < 4; ++i) {
            const int n = n0 + ng * 4 + i;
            dg[i] = (n < NN) ? deg[n] : 0.f;
        }
        const float2 bb = *(const float2*)(b2 + c0);
        float acc[4][2];
#pragma unroll
        for (int i = 0; i < 4; ++i) {
            acc[i][0] = dg[i] * bb.x;
            acc[i][1] = dg[i] * bb.y;
        }
#pragma unroll 4
        for (int k = 0; k < HH; ++k) {
            float4 h = *(const float4*)&bufT[k][ng * 4];
            float2 w = *(const float2*)(W2 + (size_t)k * DN + c0);
            const float hi[4] = {h.x, h.y, h.z, h.w};
#pragma unroll
            for (int i = 0; i < 4; ++i) {
                acc[i][0] = fmaf(hi[i], w.x, acc[i][0]);
                acc[i][1] = fmaf(hi[i], w.y, acc[i][1]);
            }
        }
        *(float4*)&xaggT[DN + c0][ng * 4] =
            make_float4(acc[0][0], acc[1][0], acc[2][0], acc[3][0]);
        *(float4*)&xaggT[DN + c0 + 1][ng * 4] =
            make_float4(acc[0][1], acc[1][1], acc[2][1], acc[3][1]);
    }
    __syncthreads();

    // ---- P2: u = relu([x,agg] @ U1 + bu1) -> bufT (u^T) ----
    {
        const int ng = t & 7;     // 8 groups * 4 nodes
        const int cg = t >> 3;    // 32 groups * 4 cols
        float acc[4][4];
        const float4 bb = *(const float4*)(bu1 + cg * 4);
#pragma unroll
        for (int i = 0; i < 4; ++i) {
            acc[i][0] = bb.x; acc[i][1] = bb.y; acc[i][2] = bb.z; acc[i][3] = bb.w;
        }
#pragma unroll 4
        for (int k = 0; k < 2 * DN; ++k) {
            float4 a = *(const float4*)&xaggT[k][ng * 4];
            float4 w = *(const float4*)(U1 + (size_t)k * HH + cg * 4);
            const float ai[4] = {a.x, a.y, a.z, a.w};
            const float wc[4] = {w.x, w.y, w.z, w.w};
#pragma unroll
            for (int i = 0; i < 4; ++i)
#pragma unroll
                for (int c = 0; c < 4; ++c) acc[i][c] = fmaf(ai[i], wc[c], acc[i][c]);
        }
        // bufT fully consumed in P1 (barrier above) -> safe to overwrite
#pragma unroll
        for (int c = 0; c < 4; ++c) {
            *(float4*)&bufT[cg * 4 + c][ng * 4] =
                make_float4(fmaxf(acc[0][c], 0.f), fmaxf(acc[1][c], 0.f),
                            fmaxf(acc[2][c], 0.f), fmaxf(acc[3][c], 0.f));
        }
    }
    __syncthreads();

    // ---- P3: out = u @ U2 + bu2 ----
    {
        const int cg = t & 31;    // 32 groups * 2 cols (fast dim -> coalesced)
        const int ng = t >> 5;    // 8 groups * 4 nodes
        const int c0 = cg * 2;
        const float2 bb = *(const float2*)(bu2 + c0);
        float acc[4][2];
#pragma unroll
        for (int i = 0; i < 4; ++i) { acc[i][0] = bb.x; acc[i][1] = bb.y; }
#pragma unroll 4
        for (int k = 0; k < HH; ++k) {
            float4 u = *(const float4*)&bufT[k][ng * 4];
            float2 w = *(const float2*)(U2 + (size_t)k * DN + c0);
            const float ui[4] = {u.x, u.y, u.z, u.w};
#pragma unroll
            for (int i = 0; i < 4; ++i) {
                acc[i][0] = fmaf(ui[i], w.x, acc[i][0]);
                acc[i][1] = fmaf(ui[i], w.y, acc[i][1]);
            }
        }
#pragma unroll
        for (int i = 0; i < 4; ++i) {
            const int n = n0 + ng * 4 + i;
            if (n < NN) {
                *(float2*)(out + (size_t)n * DN + c0) = make_float2(acc[i][0], acc[i][1]);
            }
        }
    }
}

extern "C" void kernel_launch(void* const* d_in, const int* in_sizes, int n_in,
                              void* d_out, int out_size, void* d_ws, size_t ws_size,
                              hipStream_t stream) {
    const float* x   = (const float*)d_in[0];
    const int*   ei  = (const int*)d_in[1];
    const float* ef  = (const float*)d_in[2];
    const float* W1  = (const float*)d_in[3];
    const float* b1  = (const float*)d_in[4];
    const float* W2  = (const float*)d_in[5];
    const float* b2  = (const float*)d_in[6];
    const float* U1  = (const float*)d_in[7];
    const float* bu1 = (const float*)d_in[8];
    const float* U2  = (const float*)d_in[9];
    const float* bu2 = (const float*)d_in[10];
    float* out = (float*)d_out;

    float* XA   = (float*)d_ws;                        // [NN,128]
    float* XB   = XA + (size_t)NN * HH;                // [NN,128]
    float* Hagg = XB + (size_t)NN * HH;                // [NN,128]
    float* deg  = Hagg + (size_t)NN * HH;              // [NN]
    int*   cnt  = (int*)(deg + NN);                    // [NN]
    int*   pos  = cnt + NN;                            // [NN]
    int*   boff = pos + NN;                            // [1024]
    int*   es   = boff + 1024;                         // [NE]
    float4* ef4 = (float4*)(es + NE);                  // [NE]
    const size_t need = (size_t)((char*)(ef4 + NE) - (char*)d_ws);

    const int nblk  = (NN + NT - 1) / NT;
    const int nblk2 = (NN + NT2 - 1) / NT2;

    if (ws_size >= need) {
        hipMemsetAsync(cnt, 0, (size_t)NN * sizeof(int), stream);
        k_xproj<<<nblk, 256, 0, stream>>>(x, W1, XA, XB);
        k_hist<<<(NE + 255) / 256, 256, 0, stream>>>(ei, cnt);
        k_scan_a<<<NBLK_SCAN, SCAN_B, 0, stream>>>(cnt, pos, boff);
        k_scan_b<<<1, 512, 0, stream>>>(boff);
        k_scatter<<<(NE + 255) / 256, 256, 0, stream>>>(ei, ef, pos, boff, es, ef4);
        k_agg<<<(NN + 3) / 4, 256, 0, stream>>>(es, ef4, pos, boff, cnt, XA, XB, W1, b1, Hagg, deg);
    } else {
        hipMemsetAsync(Hagg, 0, ((size_t)NN * HH + NN) * sizeof(float), stream);
        k_xproj<<<nblk, 256, 0, stream>>>(x, W1, XA, XB);
        k_edge_atomic<<<NE / 4, 256, 0, stream>>>(ei, ef, W1, b1, XA, XB, Hagg, deg);
    }
    k_update<<<nblk2, 256, 0, stream>>>(x, Hagg, deg, W2, b2, U1, bu1, U2, bu2, out);
}

// Round 5
// 501.569 us; speedup vs baseline: 2.0809x; 1.0293x over previous
//
#include <hip/hip_runtime.h>
#include <math.h>

#define NN 100000       // N_NODES
#define NE 800000       // N_EDGES
#define DN 64           // D_NODE
#define DE 4            // D_EDGE
#define HH 128          // H_MSG == H_UPD
#define NT 64           // nodes per block (k_xproj)
#define NT2 32          // nodes per block (k_update)
#define SCAN_B 256
#define NBLK_SCAN ((NN + SCAN_B - 1) / SCAN_B)   // 391

// ---------------------------------------------------------------------------
// Kernel 1: XA = x @ W1[0:64,:], XB = x @ W1[64:128,:]  (unchanged)
// ---------------------------------------------------------------------------
__global__ __launch_bounds__(256) void k_xproj(const float* __restrict__ x,
                                               const float* __restrict__ W1,
                                               float* __restrict__ XA,
                                               float* __restrict__ XB) {
    __shared__ float xsT[DN][NT];
    const int n0 = blockIdx.x * NT;
    const int t  = threadIdx.x;
    {
        const int i  = t & 63;
        const int k0 = (t >> 6) * 16;
        const int n  = n0 + i;
        if (n < NN) {
            const float4* src = (const float4*)(x + (size_t)n * DN + k0);
#pragma unroll
            for (int q = 0; q < 4; ++q) {
                float4 v = src[q];
                xsT[k0 + q * 4 + 0][i] = v.x;
                xsT[k0 + q * 4 + 1][i] = v.y;
                xsT[k0 + q * 4 + 2][i] = v.z;
                xsT[k0 + q * 4 + 3][i] = v.w;
            }
        } else {
#pragma unroll
            for (int q = 0; q < 16; ++q) xsT[k0 + q][i] = 0.f;
        }
    }
    __syncthreads();

    const int cg = t & 31;
    const int ng = t >> 5;
    const int c0 = cg * 8;
    const float* wbase = (c0 < HH) ? (W1 + c0) : (W1 + (size_t)DN * HH + (c0 - HH));

    float acc[8][8];
#pragma unroll
    for (int i = 0; i < 8; ++i)
#pragma unroll
        for (int c = 0; c < 8; ++c) acc[i][c] = 0.f;

#pragma unroll 2
    for (int k = 0; k < DN; ++k) {
        float4 xa = *(const float4*)&xsT[k][ng * 8];
        float4 xb = *(const float4*)&xsT[k][ng * 8 + 4];
        float4 w0 = *(const float4*)(wbase + (size_t)k * HH);
        float4 w1 = *(const float4*)(wbase + (size_t)k * HH + 4);
        const float xi[8] = {xa.x, xa.y, xa.z, xa.w, xb.x, xb.y, xb.z, xb.w};
        const float wc[8] = {w0.x, w0.y, w0.z, w0.w, w1.x, w1.y, w1.z, w1.w};
#pragma unroll
        for (int i = 0; i < 8; ++i)
#pragma unroll
            for (int c = 0; c < 8; ++c) acc[i][c] = fmaf(xi[i], wc[c], acc[i][c]);
    }

    float* obase = (c0 < HH) ? (XA + c0) : (XB + (c0 - HH));
#pragma unroll
    for (int i = 0; i < 8; ++i) {
        const int n = n0 + ng * 8 + i;
        if (n < NN) {
            float* dst = obase + (size_t)n * HH;
            *(float4*)(dst)     = make_float4(acc[i][0], acc[i][1], acc[i][2], acc[i][3]);
            *(float4*)(dst + 4) = make_float4(acc[i][4], acc[i][5], acc[i][6], acc[i][7]);
        }
    }
}

// ---------------------------------------------------------------------------
// Fold kernel: Wc = W2 @ U1[64:128,:]  [128,128];  cvec = b2 @ U1[64:128,:]
// ---------------------------------------------------------------------------
__global__ __launch_bounds__(256) void k_fold(const float* __restrict__ W2,
                                              const float* __restrict__ U1,
                                              const float* __restrict__ b2,
                                              float* __restrict__ Wc,
                                              float* __restrict__ cvec) {
    const int idx = blockIdx.x * 256 + threadIdx.x;
    const float* u1b = U1 + (size_t)DN * HH;   // rows 64..127
    if (blockIdx.x < 64) {
        const int r = idx >> 7;
        const int c = idx & 127;
        float acc = 0.f;
#pragma unroll 8
        for (int j = 0; j < DN; ++j)
            acc = fmaf(W2[(size_t)r * DN + j], u1b[(size_t)j * HH + c], acc);
        Wc[(size_t)r * HH + c] = acc;
    } else if (threadIdx.x < HH) {
        const int c = threadIdx.x;
        float acc = 0.f;
#pragma unroll 8
        for (int j = 0; j < DN; ++j)
            acc = fmaf(b2[j], u1b[(size_t)j * HH + c], acc);
        cvec[c] = acc;
    }
}

// ---------------------------------------------------------------------------
// Counting sort by destination (unchanged)
// ---------------------------------------------------------------------------
__global__ __launch_bounds__(256) void k_hist(const int* __restrict__ ei,
                                              int* __restrict__ cnt) {
    const int e = blockIdx.x * 256 + threadIdx.x;
    if (e < NE) atomicAdd(&cnt[ei[NE + e]], 1);
}

__global__ __launch_bounds__(SCAN_B) void k_scan_a(const int* __restrict__ cnt,
                                                   int* __restrict__ pos,
                                                   int* __restrict__ bsum) {
    __shared__ int sh[SCAN_B];
    const int n = blockIdx.x * SCAN_B + threadIdx.x;
    const int c = (n < NN) ? cnt[n] : 0;
    sh[threadIdx.x] = c;
    __syncthreads();
    int v = c;
#pragma unroll
    for (int off = 1; off < SCAN_B; off <<= 1) {
        int add = (threadIdx.x >= off) ? sh[threadIdx.x - off] : 0;
        __syncthreads();
        v += add;
        sh[threadIdx.x] = v;
        __syncthreads();
    }
    if (n < NN) pos[n] = v - c;
    if (threadIdx.x == SCAN_B - 1) bsum[blockIdx.x] = v;
}

__global__ __launch_bounds__(512) void k_scan_b(int* __restrict__ bsum) {
    __shared__ int sh[512];
    const int i = threadIdx.x;
    const int c = (i < NBLK_SCAN) ? bsum[i] : 0;
    sh[i] = c;
    __syncthreads();
    int v = c;
#pragma unroll
    for (int off = 1; off < 512; off <<= 1) {
        int add = (i >= off) ? sh[i - off] : 0;
        __syncthreads();
        v += add;
        sh[i] = v;
        __syncthreads();
    }
    if (i < NBLK_SCAN) bsum[i] = v - c;
}

__global__ __launch_bounds__(256) void k_scatter(const int* __restrict__ ei,
                                                 const float* __restrict__ ef,
                                                 int* __restrict__ pos,
                                                 const int* __restrict__ boff,
                                                 int* __restrict__ es,
                                                 float4* __restrict__ ef4) {
    const int e = blockIdx.x * 256 + threadIdx.x;
    if (e >= NE) return;
    const int s = ei[e];
    const int d = ei[NE + e];
    const int slot = atomicAdd(&pos[d], 1) + boff[d >> 8];
    es[slot] = s;
    ef4[slot] = make_float4(log1pf(ef[e * 4 + 0]), log1pf(ef[e * 4 + 1]),
                            log1pf(ef[e * 4 + 2]), log1pf(ef[e * 4 + 3]));
}

// ---------------------------------------------------------------------------
// Segmented reduce, one wave per node (unchanged from R4).
// ---------------------------------------------------------------------------
__global__ __launch_bounds__(256) void k_agg(const int* __restrict__ es,
                                             const float4* __restrict__ ef4,
                                             const int* __restrict__ pos,
                                             const int* __restrict__ boff,
                                             const int* __restrict__ cnt,
                                             const float* __restrict__ XA,
                                             const float* __restrict__ XB,
                                             const float* __restrict__ W1,
                                             const float* __restrict__ b1,
                                             float* __restrict__ Hagg,
                                             float* __restrict__ deg) {
    const int wave = threadIdx.x >> 6;
    const int lane = threadIdx.x & 63;
    const int d = blockIdx.x * 4 + wave;
    if (d >= NN) return;
    const int c     = cnt[d];
    const int end   = pos[d] + boff[d >> 8];
    const int start = end - c;
    const int j0    = lane * 2;

    const float* we = W1 + 128 * HH;
    const float2 xb = *(const float2*)(XB + (size_t)d * HH + j0);
    const float2 bb = *(const float2*)(b1 + j0);
    const float base0 = xb.x + bb.x;
    const float base1 = xb.y + bb.y;
    const float2 wv0 = *(const float2*)(we + 0 * HH + j0);
    const float2 wv1 = *(const float2*)(we + 1 * HH + j0);
    const float2 wv2 = *(const float2*)(we + 2 * HH + j0);
    const float2 wv3 = *(const float2*)(we + 3 * HH + j0);

    float acc0 = 0.f, acc1 = 0.f;
    if (c > 0) {
        float4 f_cur = ef4[start];
        float2 a_cur = *(const float2*)(XA + (size_t)es[start] * HH + j0);
        for (int k = start; k < end; ++k) {
            const float4 f = f_cur;
            const float2 a = a_cur;
            if (k + 1 < end) {
                const int sn = es[k + 1];
                f_cur = ef4[k + 1];
                a_cur = *(const float2*)(XA + (size_t)sn * HH + j0);
            }
            float h0 = a.x + base0;
            float h1 = a.y + base1;
            h0 = fmaf(f.x, wv0.x, h0); h0 = fmaf(f.y, wv1.x, h0);
            h0 = fmaf(f.z, wv2.x, h0); h0 = fmaf(f.w, wv3.x, h0);
            h1 = fmaf(f.x, wv0.y, h1); h1 = fmaf(f.y, wv1.y, h1);
            h1 = fmaf(f.z, wv2.y, h1); h1 = fmaf(f.w, wv3.y, h1);
            acc0 += fmaxf(h0, 0.f);
            acc1 += fmaxf(h1, 0.f);
        }
    }
    *(float2*)(Hagg + (size_t)d * HH + j0) = make_float2(acc0, acc1);
    if (lane == 0) deg[d] = (float)c;
}

// ---------------------------------------------------------------------------
// Fallback edge kernel (atomic path)
// ---------------------------------------------------------------------------
__global__ __launch_bounds__(256) void k_edge_atomic(const int* __restrict__ ei,
                                                     const float* __restrict__ ef,
                                                     const float* __restrict__ W1,
                                                     const float* __restrict__ b1,
                                                     const float* __restrict__ XA,
                                                     const float* __restrict__ XB,
                                                     float* __restrict__ Hagg,
                                                     float* __restrict__ deg) {
    const int wave = threadIdx.x >> 6;
    const int lane = threadIdx.x & 63;
    const long e = (long)blockIdx.x * 4 + wave;
    if (e >= NE) return;
    const int s = ei[e];
    const int d = ei[NE + e];

    float t = 0.f;
    if (lane < DE) t = log1pf(ef[e * DE + lane]);
    const float l0 = __shfl(t, 0);
    const float l1 = __shfl(t, 1);
    const float l2 = __shfl(t, 2);
    const float l3 = __shfl(t, 3);

    const float* we = W1 + 128 * HH;
    const size_t sb = (size_t)s * HH;
    const size_t db = (size_t)d * HH;
#pragma unroll
    for (int r = 0; r < 2; ++r) {
        const int j = lane + r * 64;
        float h = XA[sb + j] + XB[db + j] + b1[j];
        h = fmaf(l0, we[0 * HH + j], h);
        h = fmaf(l1, we[1 * HH + j], h);
        h = fmaf(l2, we[2 * HH + j], h);
        h = fmaf(l3, we[3 * HH + j], h);
        h = fmaxf(h, 0.f);
        atomicAdd(&Hagg[db + j], h);
    }
    if (lane == 0) atomicAdd(&deg[d], 1.f);
}

// ---------------------------------------------------------------------------
// Kernel 3 (folded): two phases, NT2=32 nodes/block, 40 KB LDS.
//   A: u  = relu(x @ U1[:64] + Hagg @ Wc + deg*cvec + bu1)   (K=192 -> 128)
//   B: out = u @ U2 + bu2                                    (K=128 -> 64)
// ---------------------------------------------------------------------------
__global__ __launch_bounds__(256) void k_update(const float* __restrict__ x,
                                                const float* __restrict__ Hagg,
                                                const float* __restrict__ deg,
                                                const float* __restrict__ U1,
                                                const float* __restrict__ Wc,
                                                const float* __restrict__ cvec,
                                                const float* __restrict__ bu1,
                                                const float* __restrict__ U2,
                                                const float* __restrict__ bu2,
                                                float* __restrict__ out) {
    __shared__ float actT[192][NT2];   // rows 0-63: x^T, 64-191: Hagg^T (24 KB)
    __shared__ float uT[HH][NT2];      // u^T (16 KB)
    __shared__ float sdeg[NT2];
    const int n0 = blockIdx.x * NT2;
    const int t  = threadIdx.x;

    // stage x^T
    {
        const int i  = t & 31;
        const int k0 = (t >> 5) * 8;
        const int n  = n0 + i;
        if (n < NN) {
            const float4* src = (const float4*)(x + (size_t)n * DN + k0);
#pragma unroll
            for (int q = 0; q < 2; ++q) {
                float4 v = src[q];
                actT[k0 + q * 4 + 0][i] = v.x;
                actT[k0 + q * 4 + 1][i] = v.y;
                actT[k0 + q * 4 + 2][i] = v.z;
                actT[k0 + q * 4 + 3][i] = v.w;
            }
        } else {
#pragma unroll
            for (int q = 0; q < 8; ++q) actT[k0 + q][i] = 0.f;
        }
    }
    // stage Hagg^T into rows 64..191
    {
        const int i  = t & 31;
        const int k0 = (t >> 5) * 16;
        const int n  = n0 + i;
        if (n < NN) {
            const float4* src = (const float4*)(Hagg + (size_t)n * HH + k0);
#pragma unroll
            for (int q = 0; q < 4; ++q) {
                float4 v = src[q];
                actT[DN + k0 + q * 4 + 0][i] = v.x;
                actT[DN + k0 + q * 4 + 1][i] = v.y;
                actT[DN + k0 + q * 4 + 2][i] = v.z;
                actT[DN + k0 + q * 4 + 3][i] = v.w;
            }
        } else {
#pragma unroll
            for (int q = 0; q < 16; ++q) actT[DN + k0 + q][i] = 0.f;
        }
    }
    if (t < NT2) sdeg[t] = (n0 + t < NN) ? deg[n0 + t] : 0.f;
    __syncthreads();

    // ---- Phase A: u = relu(x@U1a + Hagg@Wc + deg*cvec + bu1) ----
    {
        const int ng = t & 7;     // 8 groups * 4 nodes
        const int cg = t >> 3;    // 32 groups * 4 cols
        const int c0 = cg * 4;
        const float4 bb = *(const float4*)(bu1 + c0);
        const float4 cv = *(const float4*)(cvec + c0);
        float dgv[4];
#pragma unroll
        for (int i = 0; i < 4; ++i) dgv[i] = sdeg[ng * 4 + i];
        float acc[4][4];
#pragma unroll
        for (int i = 0; i < 4; ++i) {
            acc[i][0] = fmaf(dgv[i], cv.x, bb.x);
            acc[i][1] = fmaf(dgv[i], cv.y, bb.y);
            acc[i][2] = fmaf(dgv[i], cv.z, bb.z);
            acc[i][3] = fmaf(dgv[i], cv.w, bb.w);
        }
        // K1: x part (U1 rows 0..63)
#pragma unroll 4
        for (int k = 0; k < DN; ++k) {
            float4 a = *(const float4*)&actT[k][ng * 4];
            float4 w = *(const float4*)(U1 + (size_t)k * HH + c0);
            const float ai[4] = {a.x, a.y, a.z, a.w};
            const float wc[4] = {w.x, w.y, w.z, w.w};
#pragma unroll
            for (int i = 0; i < 4; ++i)
#pragma unroll
                for (int c = 0; c < 4; ++c) acc[i][c] = fmaf(ai[i], wc[c], acc[i][c]);
        }
        // K2: Hagg part (Wc rows 0..127)
#pragma unroll 4
        for (int k = 0; k < HH; ++k) {
            float4 a = *(const float4*)&actT[DN + k][ng * 4];
            float4 w = *(const float4*)(Wc + (size_t)k * HH + c0);
            const float ai[4] = {a.x, a.y, a.z, a.w};
            const float wc[4] = {w.x, w.y, w.z, w.w};
#pragma unroll
            for (int i = 0; i < 4; ++i)
#pragma unroll
                for (int c = 0; c < 4; ++c) acc[i][c] = fmaf(ai[i], wc[c], acc[i][c]);
        }
#pragma unroll
        for (int c = 0; c < 4; ++c) {
            *(float4*)&uT[c0 + c][ng * 4] =
                make_float4(fmaxf(acc[0][c], 0.f), fmaxf(acc[1][c], 0.f),
                            fmaxf(acc[2][c], 0.f), fmaxf(acc[3][c], 0.f));
        }
    }
    __syncthreads();

    // ---- Phase B: out = u @ U2 + bu2 ----
    {
        const int cg = t & 31;    // 32 groups * 2 cols (fast -> coalesced store)
        const int ng = t >> 5;    // 8 groups * 4 nodes
        const int c0 = cg * 2;
        const float2 bb = *(const float2*)(bu2 + c0);
        float acc[4][2];
#pragma unroll
        for (int i = 0; i < 4; ++i) { acc[i][0] = bb.x; acc[i][1] = bb.y; }
#pragma unroll 4
        for (int k = 0; k < HH; ++k) {
            float4 u = *(const float4*)&uT[k][ng * 4];
            float2 w = *(const float2*)(U2 + (size_t)k * DN + c0);
            const float ui[4] = {u.x, u.y, u.z, u.w};
#pragma unroll
            for (int i = 0; i < 4; ++i) {
                acc[i][0] = fmaf(ui[i], w.x, acc[i][0]);
                acc[i][1] = fmaf(ui[i], w.y, acc[i][1]);
            }
        }
#pragma unroll
        for (int i = 0; i < 4; ++i) {
            const int n = n0 + ng * 4 + i;
            if (n < NN) {
                *(float2*)(out + (size_t)n * DN + c0) = make_float2(acc[i][0], acc[i][1]);
            }
        }
    }
}

extern "C" void kernel_launch(void* const* d_in, const int* in_sizes, int n_in,
                              void* d_out, int out_size, void* d_ws, size_t ws_size,
                              hipStream_t stream) {
    const float* x   = (const float*)d_in[0];
    const int*   ei  = (const int*)d_in[1];
    const float* ef  = (const float*)d_in[2];
    const float* W1  = (const float*)d_in[3];
    const float* b1  = (const float*)d_in[4];
    const float* W2  = (const float*)d_in[5];
    const float* b2  = (const float*)d_in[6];
    const float* U1  = (const float*)d_in[7];
    const float* bu1 = (const float*)d_in[8];
    const float* U2  = (const float*)d_in[9];
    const float* bu2 = (const float*)d_in[10];
    float* out = (float*)d_out;

    float* XA   = (float*)d_ws;                        // [NN,128]
    float* XB   = XA + (size_t)NN * HH;                // [NN,128]
    float* Hagg = XB + (size_t)NN * HH;                // [NN,128]
    float* deg  = Hagg + (size_t)NN * HH;              // [NN]
    float* Wc   = deg + NN;                            // [128,128]
    float* cvec = Wc + (size_t)HH * HH;                // [128]
    int*   cnt  = (int*)(cvec + HH);                   // [NN]
    int*   pos  = cnt + NN;                            // [NN]
    int*   boff = pos + NN;                            // [1024]
    int*   es   = boff + 1024;                         // [NE]
    float4* ef4 = (float4*)(es + NE);                  // [NE]
    const size_t need = (size_t)((char*)(ef4 + NE) - (char*)d_ws);

    const int nblk  = (NN + NT - 1) / NT;
    const int nblk2 = (NN + NT2 - 1) / NT2;

    k_fold<<<65, 256, 0, stream>>>(W2, U1, b2, Wc, cvec);

    if (ws_size >= need) {
        hipMemsetAsync(cnt, 0, (size_t)NN * sizeof(int), stream);
        k_xproj<<<nblk, 256, 0, stream>>>(x, W1, XA, XB);
        k_hist<<<(NE + 255) / 256, 256, 0, stream>>>(ei, cnt);
        k_scan_a<<<NBLK_SCAN, SCAN_B, 0, stream>>>(cnt, pos, boff);
        k_scan_b<<<1, 512, 0, stream>>>(boff);
        k_scatter<<<(NE + 255) / 256, 256, 0, stream>>>(ei, ef, pos, boff, es, ef4);
        k_agg<<<(NN + 3) / 4, 256, 0, stream>>>(es, ef4, pos, boff, cnt, XA, XB, W1, b1, Hagg, deg);
    } else {
        hipMemsetAsync(Hagg, 0, ((size_t)NN * HH + NN) * sizeof(float), stream);
        k_xproj<<<nblk, 256, 0, stream>>>(x, W1, XA, XB);
        k_edge_atomic<<<NE / 4, 256, 0, stream>>>(ei, ef, W1, b1, XA, XB, Hagg, deg);
    }
    k_update<<<nblk2, 256, 0, stream>>>(x, Hagg, deg, U1, Wc, cvec, bu1, U2, bu2, out);
}

// Round 6
// 482.709 us; speedup vs baseline: 2.1622x; 1.0391x over previous
//
#include <hip/hip_runtime.h>
#include <math.h>

#define NN 100000       // N_NODES
#define NE 800000       // N_EDGES
#define DN 64           // D_NODE
#define DE 4            // D_EDGE
#define HH 128          // H_MSG == H_UPD
#define NT 64           // nodes per block (k_xproj)
#define NT2 32          // nodes per block (k_update)
#define SCAN_B 256
#define NBLK_SCAN ((NN + SCAN_B - 1) / SCAN_B)   // 391

// bf16 helpers (manual, RNE)
__device__ __forceinline__ unsigned short f2bf(float f) {
    unsigned int u = __float_as_uint(f);
    unsigned int r = (u + 0x7fffu + ((u >> 16) & 1u)) >> 16;
    return (unsigned short)r;
}
__device__ __forceinline__ float bf2f(unsigned short h) {
    return __uint_as_float(((unsigned int)h) << 16);
}
__device__ __forceinline__ float2 bfpair2f(unsigned int v) {
    return make_float2(__uint_as_float(v << 16),
                       __uint_as_float(v & 0xffff0000u));
}

// ---------------------------------------------------------------------------
// Kernel 1: XA(bf16) = x @ W1[0:64,:], XB(f32) = x @ W1[64:128,:]
// ---------------------------------------------------------------------------
__global__ __launch_bounds__(256) void k_xproj(const float* __restrict__ x,
                                               const float* __restrict__ W1,
                                               unsigned short* __restrict__ XAb,
                                               float* __restrict__ XB) {
    __shared__ float xsT[DN][NT];
    const int n0 = blockIdx.x * NT;
    const int t  = threadIdx.x;
    {
        const int i  = t & 63;
        const int k0 = (t >> 6) * 16;
        const int n  = n0 + i;
        if (n < NN) {
            const float4* src = (const float4*)(x + (size_t)n * DN + k0);
#pragma unroll
            for (int q = 0; q < 4; ++q) {
                float4 v = src[q];
                xsT[k0 + q * 4 + 0][i] = v.x;
                xsT[k0 + q * 4 + 1][i] = v.y;
                xsT[k0 + q * 4 + 2][i] = v.z;
                xsT[k0 + q * 4 + 3][i] = v.w;
            }
        } else {
#pragma unroll
            for (int q = 0; q < 16; ++q) xsT[k0 + q][i] = 0.f;
        }
    }
    __syncthreads();

    const int cg = t & 31;
    const int ng = t >> 5;
    const int c0 = cg * 8;
    const float* wbase = (c0 < HH) ? (W1 + c0) : (W1 + (size_t)DN * HH + (c0 - HH));

    float acc[8][8];
#pragma unroll
    for (int i = 0; i < 8; ++i)
#pragma unroll
        for (int c = 0; c < 8; ++c) acc[i][c] = 0.f;

#pragma unroll 2
    for (int k = 0; k < DN; ++k) {
        float4 xa = *(const float4*)&xsT[k][ng * 8];
        float4 xb = *(const float4*)&xsT[k][ng * 8 + 4];
        float4 w0 = *(const float4*)(wbase + (size_t)k * HH);
        float4 w1 = *(const float4*)(wbase + (size_t)k * HH + 4);
        const float xi[8] = {xa.x, xa.y, xa.z, xa.w, xb.x, xb.y, xb.z, xb.w};
        const float wc[8] = {w0.x, w0.y, w0.z, w0.w, w1.x, w1.y, w1.z, w1.w};
#pragma unroll
        for (int i = 0; i < 8; ++i)
#pragma unroll
            for (int c = 0; c < 8; ++c) acc[i][c] = fmaf(xi[i], wc[c], acc[i][c]);
    }

    if (c0 < HH) {
        // XA in bf16: 8 cols -> 16 bytes
#pragma unroll
        for (int i = 0; i < 8; ++i) {
            const int n = n0 + ng * 8 + i;
            if (n < NN) {
                unsigned short tmp[8];
#pragma unroll
                for (int c = 0; c < 8; ++c) tmp[c] = f2bf(acc[i][c]);
                *(uint4*)(XAb + (size_t)n * HH + c0) = *(const uint4*)tmp;
            }
        }
    } else {
#pragma unroll
        for (int i = 0; i < 8; ++i) {
            const int n = n0 + ng * 8 + i;
            if (n < NN) {
                float* dst = XB + (size_t)n * HH + (c0 - HH);
                *(float4*)(dst)     = make_float4(acc[i][0], acc[i][1], acc[i][2], acc[i][3]);
                *(float4*)(dst + 4) = make_float4(acc[i][4], acc[i][5], acc[i][6], acc[i][7]);
            }
        }
    }
}

// ---------------------------------------------------------------------------
// Fold kernel: Wc = W2 @ U1[64:128,:];  cvec = b2 @ U1[64:128,:]
// ---------------------------------------------------------------------------
__global__ __launch_bounds__(256) void k_fold(const float* __restrict__ W2,
                                              const float* __restrict__ U1,
                                              const float* __restrict__ b2,
                                              float* __restrict__ Wc,
                                              float* __restrict__ cvec) {
    const int idx = blockIdx.x * 256 + threadIdx.x;
    const float* u1b = U1 + (size_t)DN * HH;
    if (blockIdx.x < 64) {
        const int r = idx >> 7;
        const int c = idx & 127;
        float acc = 0.f;
#pragma unroll 8
        for (int j = 0; j < DN; ++j)
            acc = fmaf(W2[(size_t)r * DN + j], u1b[(size_t)j * HH + c], acc);
        Wc[(size_t)r * HH + c] = acc;
    } else if (threadIdx.x < HH) {
        const int c = threadIdx.x;
        float acc = 0.f;
#pragma unroll 8
        for (int j = 0; j < DN; ++j)
            acc = fmaf(b2[j], u1b[(size_t)j * HH + c], acc);
        cvec[c] = acc;
    }
}

// ---------------------------------------------------------------------------
// Counting sort by destination
// ---------------------------------------------------------------------------
__global__ __launch_bounds__(256) void k_hist(const int* __restrict__ ei,
                                              int* __restrict__ cnt) {
    const int e = blockIdx.x * 256 + threadIdx.x;
    if (e < NE) atomicAdd(&cnt[ei[NE + e]], 1);
}

__global__ __launch_bounds__(SCAN_B) void k_scan_a(const int* __restrict__ cnt,
                                                   int* __restrict__ pos,
                                                   int* __restrict__ bsum) {
    __shared__ int sh[SCAN_B];
    const int n = blockIdx.x * SCAN_B + threadIdx.x;
    const int c = (n < NN) ? cnt[n] : 0;
    sh[threadIdx.x] = c;
    __syncthreads();
    int v = c;
#pragma unroll
    for (int off = 1; off < SCAN_B; off <<= 1) {
        int add = (threadIdx.x >= off) ? sh[threadIdx.x - off] : 0;
        __syncthreads();
        v += add;
        sh[threadIdx.x] = v;
        __syncthreads();
    }
    if (n < NN) pos[n] = v - c;
    if (threadIdx.x == SCAN_B - 1) bsum[blockIdx.x] = v;
}

__global__ __launch_bounds__(512) void k_scan_b(int* __restrict__ bsum) {
    __shared__ int sh[512];
    const int i = threadIdx.x;
    const int c = (i < NBLK_SCAN) ? bsum[i] : 0;
    sh[i] = c;
    __syncthreads();
    int v = c;
#pragma unroll
    for (int off = 1; off < 512; off <<= 1) {
        int add = (i >= off) ? sh[i - off] : 0;
        __syncthreads();
        v += add;
        sh[i] = v;
        __syncthreads();
    }
    if (i < NBLK_SCAN) bsum[i] = v - c;
}

__global__ __launch_bounds__(256) void k_scatter(const int* __restrict__ ei,
                                                 const float* __restrict__ ef,
                                                 int* __restrict__ pos,
                                                 const int* __restrict__ boff,
                                                 int* __restrict__ es,
                                                 float4* __restrict__ ef4) {
    const int e = blockIdx.x * 256 + threadIdx.x;
    if (e >= NE) return;
    const int s = ei[e];
    const int d = ei[NE + e];
    const int slot = atomicAdd(&pos[d], 1) + boff[d >> 8];
    es[slot] = s;
    ef4[slot] = make_float4(log1pf(ef[e * 4 + 0]), log1pf(ef[e * 4 + 1]),
                            log1pf(ef[e * 4 + 2]), log1pf(ef[e * 4 + 3]));
}

// ---------------------------------------------------------------------------
// Segmented reduce, one wave per node. XA gather is bf16: ONE dword per lane
// (256 B per row per wave). 2-deep software pipeline on the es->XA chain.
// ---------------------------------------------------------------------------
__global__ __launch_bounds__(256) void k_agg(const int* __restrict__ es,
                                             const float4* __restrict__ ef4,
                                             const int* __restrict__ pos,
                                             const int* __restrict__ boff,
                                             const int* __restrict__ cnt,
                                             const unsigned short* __restrict__ XAb,
                                             const float* __restrict__ XB,
                                             const float* __restrict__ W1,
                                             const float* __restrict__ b1,
                                             float* __restrict__ Hagg,
                                             float* __restrict__ deg) {
    const int wave = threadIdx.x >> 6;
    const int lane = threadIdx.x & 63;
    const int d = blockIdx.x * 4 + wave;
    if (d >= NN) return;
    const int c     = cnt[d];
    const int end   = pos[d] + boff[d >> 8];
    const int start = end - c;
    const int j0    = lane * 2;

    const float* we = W1 + 128 * HH;
    const float2 xb = *(const float2*)(XB + (size_t)d * HH + j0);
    const float2 bb = *(const float2*)(b1 + j0);
    const float base0 = xb.x + bb.x;
    const float base1 = xb.y + bb.y;
    const float2 wv0 = *(const float2*)(we + 0 * HH + j0);
    const float2 wv1 = *(const float2*)(we + 1 * HH + j0);
    const float2 wv2 = *(const float2*)(we + 2 * HH + j0);
    const float2 wv3 = *(const float2*)(we + 3 * HH + j0);

    float acc0 = 0.f, acc1 = 0.f;
    if (c > 0) {
        float4 f_cur = ef4[start];
        unsigned int a_cur = *(const unsigned int*)(XAb + (size_t)es[start] * HH + j0);
        for (int k = start; k < end; ++k) {
            const float4 f = f_cur;
            const float2 a = bfpair2f(a_cur);
            if (k + 1 < end) {
                const int sn = es[k + 1];
                f_cur = ef4[k + 1];
                a_cur = *(const unsigned int*)(XAb + (size_t)sn * HH + j0);
            }
            float h0 = a.x + base0;
            float h1 = a.y + base1;
            h0 = fmaf(f.x, wv0.x, h0); h0 = fmaf(f.y, wv1.x, h0);
            h0 = fmaf(f.z, wv2.x, h0); h0 = fmaf(f.w, wv3.x, h0);
            h1 = fmaf(f.x, wv0.y, h1); h1 = fmaf(f.y, wv1.y, h1);
            h1 = fmaf(f.z, wv2.y, h1); h1 = fmaf(f.w, wv3.y, h1);
            acc0 += fmaxf(h0, 0.f);
            acc1 += fmaxf(h1, 0.f);
        }
    }
    *(float2*)(Hagg + (size_t)d * HH + j0) = make_float2(acc0, acc1);
    if (lane == 0) deg[d] = (float)c;
}

// ---------------------------------------------------------------------------
// Fallback edge kernel (atomic path)
// ---------------------------------------------------------------------------
__global__ __launch_bounds__(256) void k_edge_atomic(const int* __restrict__ ei,
                                                     const float* __restrict__ ef,
                                                     const float* __restrict__ W1,
                                                     const float* __restrict__ b1,
                                                     const unsigned short* __restrict__ XAb,
                                                     const float* __restrict__ XB,
                                                     float* __restrict__ Hagg,
                                                     float* __restrict__ deg) {
    const int wave = threadIdx.x >> 6;
    const int lane = threadIdx.x & 63;
    const long e = (long)blockIdx.x * 4 + wave;
    if (e >= NE) return;
    const int s = ei[e];
    const int d = ei[NE + e];

    float t = 0.f;
    if (lane < DE) t = log1pf(ef[e * DE + lane]);
    const float l0 = __shfl(t, 0);
    const float l1 = __shfl(t, 1);
    const float l2 = __shfl(t, 2);
    const float l3 = __shfl(t, 3);

    const float* we = W1 + 128 * HH;
    const size_t sb = (size_t)s * HH;
    const size_t db = (size_t)d * HH;
#pragma unroll
    for (int r = 0; r < 2; ++r) {
        const int j = lane + r * 64;
        float h = bf2f(XAb[sb + j]) + XB[db + j] + b1[j];
        h = fmaf(l0, we[0 * HH + j], h);
        h = fmaf(l1, we[1 * HH + j], h);
        h = fmaf(l2, we[2 * HH + j], h);
        h = fmaf(l3, we[3 * HH + j], h);
        h = fmaxf(h, 0.f);
        atomicAdd(&Hagg[db + j], h);
    }
    if (lane == 0) atomicAdd(&deg[d], 1.f);
}

// ---------------------------------------------------------------------------
// Kernel 3 (folded): NT2=32 nodes/block, 24.2 KB LDS (uT aliased into actT).
//   A: u  = relu(x @ U1[:64] + Hagg @ Wc + deg*cvec + bu1)   (K=192 -> 128)
//   B: out = u @ U2 + bu2                                    (K=128 -> 64)
// ---------------------------------------------------------------------------
__global__ __launch_bounds__(256) void k_update(const float* __restrict__ x,
                                                const float* __restrict__ Hagg,
                                                const float* __restrict__ deg,
                                                const float* __restrict__ U1,
                                                const float* __restrict__ Wc,
                                                const float* __restrict__ cvec,
                                                const float* __restrict__ bu1,
                                                const float* __restrict__ U2,
                                                const float* __restrict__ bu2,
                                                float* __restrict__ out) {
    __shared__ float actT[192][NT2];   // rows 0-63 x^T, 64-191 Hagg^T; rows 0-127 reused as u^T
    __shared__ float sdeg[NT2];
    const int n0 = blockIdx.x * NT2;
    const int t  = threadIdx.x;

    // stage x^T
    {
        const int i  = t & 31;
        const int k0 = (t >> 5) * 8;
        const int n  = n0 + i;
        if (n < NN) {
            const float4* src = (const float4*)(x + (size_t)n * DN + k0);
#pragma unroll
            for (int q = 0; q < 2; ++q) {
                float4 v = src[q];
                actT[k0 + q * 4 + 0][i] = v.x;
                actT[k0 + q * 4 + 1][i] = v.y;
                actT[k0 + q * 4 + 2][i] = v.z;
                actT[k0 + q * 4 + 3][i] = v.w;
            }
        } else {
#pragma unroll
            for (int q = 0; q < 8; ++q) actT[k0 + q][i] = 0.f;
        }
    }
    // stage Hagg^T into rows 64..191
    {
        const int i  = t & 31;
        const int k0 = (t >> 5) * 16;
        const int n  = n0 + i;
        if (n < NN) {
            const float4* src = (const float4*)(Hagg + (size_t)n * HH + k0);
#pragma unroll
            for (int q = 0; q < 4; ++q) {
                float4 v = src[q];
                actT[DN + k0 + q * 4 + 0][i] = v.x;
                actT[DN + k0 + q * 4 + 1][i] = v.y;
                actT[DN + k0 + q * 4 + 2][i] = v.z;
                actT[DN + k0 + q * 4 + 3][i] = v.w;
            }
        } else {
#pragma unroll
            for (int q = 0; q < 16; ++q) actT[DN + k0 + q][i] = 0.f;
        }
    }
    if (t < NT2) sdeg[t] = (n0 + t < NN) ? deg[n0 + t] : 0.f;
    __syncthreads();

    const int ng = t & 7;     // 8 groups * 4 nodes
    const int cgA = t >> 3;   // 32 groups * 4 cols
    const int cA = cgA * 4;

    // ---- Phase A: u = relu(x@U1a + Hagg@Wc + deg*cvec + bu1) ----
    float acc[4][4];
    {
        const float4 bb = *(const float4*)(bu1 + cA);
        const float4 cv = *(const float4*)(cvec + cA);
        float dgv[4];
#pragma unroll
        for (int i = 0; i < 4; ++i) dgv[i] = sdeg[ng * 4 + i];
#pragma unroll
        for (int i = 0; i < 4; ++i) {
            acc[i][0] = fmaf(dgv[i], cv.x, bb.x);
            acc[i][1] = fmaf(dgv[i], cv.y, bb.y);
            acc[i][2] = fmaf(dgv[i], cv.z, bb.z);
            acc[i][3] = fmaf(dgv[i], cv.w, bb.w);
        }
        // K1: x part (U1 rows 0..63) with 1-deep weight prefetch
        const float* wp = U1 + cA;
        float4 w_nxt = *(const float4*)(wp);
#pragma unroll 4
        for (int k = 0; k < DN; ++k) {
            const float4 w = w_nxt;
            if (k + 1 < DN) w_nxt = *(const float4*)(wp + (size_t)(k + 1) * HH);
            float4 a = *(const float4*)&actT[k][ng * 4];
            const float ai[4] = {a.x, a.y, a.z, a.w};
            const float wc[4] = {w.x, w.y, w.z, w.w};
#pragma unroll
            for (int i = 0; i < 4; ++i)
#pragma unroll
                for (int c = 0; c < 4; ++c) acc[i][c] = fmaf(ai[i], wc[c], acc[i][c]);
        }
        // K2: Hagg part (Wc rows 0..127) with 1-deep weight prefetch
        const float* wp2 = Wc + cA;
        w_nxt = *(const float4*)(wp2);
#pragma unroll 4
        for (int k = 0; k < HH; ++k) {
            const float4 w = w_nxt;
            if (k + 1 < HH) w_nxt = *(const float4*)(wp2 + (size_t)(k + 1) * HH);
            float4 a = *(const float4*)&actT[DN + k][ng * 4];
            const float ai[4] = {a.x, a.y, a.z, a.w};
            const float wc[4] = {w.x, w.y, w.z, w.w};
#pragma unroll
            for (int i = 0; i < 4; ++i)
#pragma unroll
                for (int c = 0; c < 4; ++c) acc[i][c] = fmaf(ai[i], wc[c], acc[i][c]);
        }
    }
    __syncthreads();   // all reads of actT complete -> safe to overwrite rows 0..127

    // write u^T into actT rows 0..127
#pragma unroll
    for (int c = 0; c < 4; ++c) {
        *(float4*)&actT[cA + c][ng * 4] =
            make_float4(fmaxf(acc[0][c], 0.f), fmaxf(acc[1][c], 0.f),
                        fmaxf(acc[2][c], 0.f), fmaxf(acc[3][c], 0.f));
    }
    __syncthreads();

    // ---- Phase B: out = u @ U2 + bu2 ----
    {
        const int cg = t & 31;    // 32 groups * 2 cols (fast -> coalesced store)
        const int ngB = t >> 5;   // 8 groups * 4 nodes
        const int c0 = cg * 2;
        const float2 bb = *(const float2*)(bu2 + c0);
        float accB[4][2];
#pragma unroll
        for (int i = 0; i < 4; ++i) { accB[i][0] = bb.x; accB[i][1] = bb.y; }
        const float* wp = U2 + c0;
        float2 w_nxt = *(const float2*)(wp);
#pragma unroll 4
        for (int k = 0; k < HH; ++k) {
            const float2 w = w_nxt;
            if (k + 1 < HH) w_nxt = *(const float2*)(wp + (size_t)(k + 1) * DN);
            float4 u = *(const float4*)&actT[k][ngB * 4];
            const float ui[4] = {u.x, u.y, u.z, u.w};
#pragma unroll
            for (int i = 0; i < 4; ++i) {
                accB[i][0] = fmaf(ui[i], w.x, accB[i][0]);
                accB[i][1] = fmaf(ui[i], w.y, accB[i][1]);
            }
        }
#pragma unroll
        for (int i = 0; i < 4; ++i) {
            const int n = n0 + ngB * 4 + i;
            if (n < NN) {
                *(float2*)(out + (size_t)n * DN + c0) = make_float2(accB[i][0], accB[i][1]);
            }
        }
    }
}

extern "C" void kernel_launch(void* const* d_in, const int* in_sizes, int n_in,
                              void* d_out, int out_size, void* d_ws, size_t ws_size,
                              hipStream_t stream) {
    const float* x   = (const float*)d_in[0];
    const int*   ei  = (const int*)d_in[1];
    const float* ef  = (const float*)d_in[2];
    const float* W1  = (const float*)d_in[3];
    const float* b1  = (const float*)d_in[4];
    const float* W2  = (const float*)d_in[5];
    const float* b2  = (const float*)d_in[6];
    const float* U1  = (const float*)d_in[7];
    const float* bu1 = (const float*)d_in[8];
    const float* U2  = (const float*)d_in[9];
    const float* bu2 = (const float*)d_in[10];
    float* out = (float*)d_out;

    unsigned short* XAb = (unsigned short*)d_ws;       // [NN,128] bf16, 25.6 MB
    float* XB   = (float*)(XAb + (size_t)NN * HH);     // [NN,128] f32
    float* Hagg = XB + (size_t)NN * HH;                // [NN,128]
    float* deg  = Hagg + (size_t)NN * HH;              // [NN]
    float* Wc   = deg + NN;                            // [128,128]
    float* cvec = Wc + (size_t)HH * HH;                // [128]
    int*   cnt  = (int*)(cvec + HH);                   // [NN]
    int*   pos  = cnt + NN;                            // [NN]
    int*   boff = pos + NN;                            // [1024]
    int*   es   = boff + 1024;                         // [NE]
    float4* ef4 = (float4*)(es + NE);                  // [NE]
    const size_t need = (size_t)((char*)(ef4 + NE) - (char*)d_ws);

    const int nblk  = (NN + NT - 1) / NT;
    const int nblk2 = (NN + NT2 - 1) / NT2;

    k_fold<<<65, 256, 0, stream>>>(W2, U1, b2, Wc, cvec);

    if (ws_size >= need) {
        hipMemsetAsync(cnt, 0, (size_t)NN * sizeof(int), stream);
        k_xproj<<<nblk, 256, 0, stream>>>(x, W1, XAb, XB);
        k_hist<<<(NE + 255) / 256, 256, 0, stream>>>(ei, cnt);
        k_scan_a<<<NBLK_SCAN, SCAN_B, 0, stream>>>(cnt, pos, boff);
        k_scan_b<<<1, 512, 0, stream>>>(boff);
        k_scatter<<<(NE + 255) / 256, 256, 0, stream>>>(ei, ef, pos, boff, es, ef4);
        k_agg<<<(NN + 3) / 4, 256, 0, stream>>>(es, ef4, pos, boff, cnt, XAb, XB, W1, b1, Hagg, deg);
    } else {
        hipMemsetAsync(Hagg, 0, ((size_t)NN * HH + NN) * sizeof(float), stream);
        k_xproj<<<nblk, 256, 0, stream>>>(x, W1, XAb, XB);
        k_edge_atomic<<<NE / 4, 256, 0, stream>>>(ei, ef, W1, b1, XAb, XB, Hagg, deg);
    }
    k_update<<<nblk2, 256, 0, stream>>>(x, Hagg, deg, U1, Wc, cvec, bu1, U2, bu2, out);
}

// Round 7
// 458.521 us; speedup vs baseline: 2.2763x; 1.0528x over previous
//
#include <hip/hip_runtime.h>
#include <math.h>

#define NN 100000       // N_NODES
#define NE 800000       // N_EDGES
#define DN 64           // D_NODE
#define DE 4            // D_EDGE
#define HH 128          // H_MSG == H_UPD
#define NT 64           // nodes per block (k_xproj)
#define NT2 64          // nodes per block (k_update)
#define SCAN_B 256
#define NBLK_SCAN ((NN + SCAN_B - 1) / SCAN_B)   // 391

// bf16 helpers (manual, RNE)
__device__ __forceinline__ unsigned short f2bf(float f) {
    unsigned int u = __float_as_uint(f);
    unsigned int r = (u + 0x7fffu + ((u >> 16) & 1u)) >> 16;
    return (unsigned short)r;
}
__device__ __forceinline__ float bf2f(unsigned short h) {
    return __uint_as_float(((unsigned int)h) << 16);
}
__device__ __forceinline__ float2 bfpair2f(unsigned int v) {
    return make_float2(__uint_as_float(v << 16),
                       __uint_as_float(v & 0xffff0000u));
}

// ---------------------------------------------------------------------------
// Kernel 1: XA(bf16) = x @ W1[0:64,:], XB(f32) = x @ W1[64:128,:]
// ---------------------------------------------------------------------------
__global__ __launch_bounds__(256) void k_xproj(const float* __restrict__ x,
                                               const float* __restrict__ W1,
                                               unsigned short* __restrict__ XAb,
                                               float* __restrict__ XB) {
    __shared__ float xsT[DN][NT];
    const int n0 = blockIdx.x * NT;
    const int t  = threadIdx.x;
    {
        const int i  = t & 63;
        const int k0 = (t >> 6) * 16;
        const int n  = n0 + i;
        if (n < NN) {
            const float4* src = (const float4*)(x + (size_t)n * DN + k0);
#pragma unroll
            for (int q = 0; q < 4; ++q) {
                float4 v = src[q];
                xsT[k0 + q * 4 + 0][i] = v.x;
                xsT[k0 + q * 4 + 1][i] = v.y;
                xsT[k0 + q * 4 + 2][i] = v.z;
                xsT[k0 + q * 4 + 3][i] = v.w;
            }
        } else {
#pragma unroll
            for (int q = 0; q < 16; ++q) xsT[k0 + q][i] = 0.f;
        }
    }
    __syncthreads();

    const int cg = t & 31;
    const int ng = t >> 5;
    const int c0 = cg * 8;
    const float* wbase = (c0 < HH) ? (W1 + c0) : (W1 + (size_t)DN * HH + (c0 - HH));

    float acc[8][8];
#pragma unroll
    for (int i = 0; i < 8; ++i)
#pragma unroll
        for (int c = 0; c < 8; ++c) acc[i][c] = 0.f;

#pragma unroll 2
    for (int k = 0; k < DN; ++k) {
        float4 xa = *(const float4*)&xsT[k][ng * 8];
        float4 xb = *(const float4*)&xsT[k][ng * 8 + 4];
        float4 w0 = *(const float4*)(wbase + (size_t)k * HH);
        float4 w1 = *(const float4*)(wbase + (size_t)k * HH + 4);
        const float xi[8] = {xa.x, xa.y, xa.z, xa.w, xb.x, xb.y, xb.z, xb.w};
        const float wc[8] = {w0.x, w0.y, w0.z, w0.w, w1.x, w1.y, w1.z, w1.w};
#pragma unroll
        for (int i = 0; i < 8; ++i)
#pragma unroll
            for (int c = 0; c < 8; ++c) acc[i][c] = fmaf(xi[i], wc[c], acc[i][c]);
    }

    if (c0 < HH) {
#pragma unroll
        for (int i = 0; i < 8; ++i) {
            const int n = n0 + ng * 8 + i;
            if (n < NN) {
                unsigned short tmp[8];
#pragma unroll
                for (int c = 0; c < 8; ++c) tmp[c] = f2bf(acc[i][c]);
                *(uint4*)(XAb + (size_t)n * HH + c0) = *(const uint4*)tmp;
            }
        }
    } else {
#pragma unroll
        for (int i = 0; i < 8; ++i) {
            const int n = n0 + ng * 8 + i;
            if (n < NN) {
                float* dst = XB + (size_t)n * HH + (c0 - HH);
                *(float4*)(dst)     = make_float4(acc[i][0], acc[i][1], acc[i][2], acc[i][3]);
                *(float4*)(dst + 4) = make_float4(acc[i][4], acc[i][5], acc[i][6], acc[i][7]);
            }
        }
    }
}

// ---------------------------------------------------------------------------
// Fold kernel: Wc = W2 @ U1[64:128,:];  cvec = b2 @ U1[64:128,:]
// ---------------------------------------------------------------------------
__global__ __launch_bounds__(256) void k_fold(const float* __restrict__ W2,
                                              const float* __restrict__ U1,
                                              const float* __restrict__ b2,
                                              float* __restrict__ Wc,
                                              float* __restrict__ cvec) {
    const int idx = blockIdx.x * 256 + threadIdx.x;
    const float* u1b = U1 + (size_t)DN * HH;
    if (blockIdx.x < 64) {
        const int r = idx >> 7;
        const int c = idx & 127;
        float acc = 0.f;
#pragma unroll 8
        for (int j = 0; j < DN; ++j)
            acc = fmaf(W2[(size_t)r * DN + j], u1b[(size_t)j * HH + c], acc);
        Wc[(size_t)r * HH + c] = acc;
    } else if (threadIdx.x < HH) {
        const int c = threadIdx.x;
        float acc = 0.f;
#pragma unroll 8
        for (int j = 0; j < DN; ++j)
            acc = fmaf(b2[j], u1b[(size_t)j * HH + c], acc);
        cvec[c] = acc;
    }
}

// ---------------------------------------------------------------------------
// Counting sort by destination
// ---------------------------------------------------------------------------
__global__ __launch_bounds__(256) void k_hist(const int* __restrict__ ei,
                                              int* __restrict__ cnt) {
    const int e = blockIdx.x * 256 + threadIdx.x;
    if (e < NE) atomicAdd(&cnt[ei[NE + e]], 1);
}

__global__ __launch_bounds__(SCAN_B) void k_scan_a(const int* __restrict__ cnt,
                                                   int* __restrict__ pos,
                                                   int* __restrict__ bsum) {
    __shared__ int sh[SCAN_B];
    const int n = blockIdx.x * SCAN_B + threadIdx.x;
    const int c = (n < NN) ? cnt[n] : 0;
    sh[threadIdx.x] = c;
    __syncthreads();
    int v = c;
#pragma unroll
    for (int off = 1; off < SCAN_B; off <<= 1) {
        int add = (threadIdx.x >= off) ? sh[threadIdx.x - off] : 0;
        __syncthreads();
        v += add;
        sh[threadIdx.x] = v;
        __syncthreads();
    }
    if (n < NN) pos[n] = v - c;
    if (threadIdx.x == SCAN_B - 1) bsum[blockIdx.x] = v;
}

__global__ __launch_bounds__(512) void k_scan_b(int* __restrict__ bsum) {
    __shared__ int sh[512];
    const int i = threadIdx.x;
    const int c = (i < NBLK_SCAN) ? bsum[i] : 0;
    sh[i] = c;
    __syncthreads();
    int v = c;
#pragma unroll
    for (int off = 1; off < 512; off <<= 1) {
        int add = (i >= off) ? sh[i - off] : 0;
        __syncthreads();
        v += add;
        sh[i] = v;
        __syncthreads();
    }
    if (i < NBLK_SCAN) bsum[i] = v - c;
}

__global__ __launch_bounds__(256) void k_scatter(const int* __restrict__ ei,
                                                 const float* __restrict__ ef,
                                                 int* __restrict__ pos,
                                                 const int* __restrict__ boff,
                                                 int* __restrict__ es,
                                                 float4* __restrict__ ef4) {
    const int e = blockIdx.x * 256 + threadIdx.x;
    if (e >= NE) return;
    const int s = ei[e];
    const int d = ei[NE + e];
    const int slot = atomicAdd(&pos[d], 1) + boff[d >> 8];
    es[slot] = s;
    ef4[slot] = make_float4(log1pf(ef[e * 4 + 0]), log1pf(ef[e * 4 + 1]),
                            log1pf(ef[e * 4 + 2]), log1pf(ef[e * 4 + 3]));
}

// ---------------------------------------------------------------------------
// Segmented reduce, one wave per node (unchanged from R6).
// ---------------------------------------------------------------------------
__global__ __launch_bounds__(256) void k_agg(const int* __restrict__ es,
                                             const float4* __restrict__ ef4,
                                             const int* __restrict__ pos,
                                             const int* __restrict__ boff,
                                             const int* __restrict__ cnt,
                                             const unsigned short* __restrict__ XAb,
                                             const float* __restrict__ XB,
                                             const float* __restrict__ W1,
                                             const float* __restrict__ b1,
                                             float* __restrict__ Hagg,
                                             float* __restrict__ deg) {
    const int wave = threadIdx.x >> 6;
    const int lane = threadIdx.x & 63;
    const int d = blockIdx.x * 4 + wave;
    if (d >= NN) return;
    const int c     = cnt[d];
    const int end   = pos[d] + boff[d >> 8];
    const int start = end - c;
    const int j0    = lane * 2;

    const float* we = W1 + 128 * HH;
    const float2 xb = *(const float2*)(XB + (size_t)d * HH + j0);
    const float2 bb = *(const float2*)(b1 + j0);
    const float base0 = xb.x + bb.x;
    const float base1 = xb.y + bb.y;
    const float2 wv0 = *(const float2*)(we + 0 * HH + j0);
    const float2 wv1 = *(const float2*)(we + 1 * HH + j0);
    const float2 wv2 = *(const float2*)(we + 2 * HH + j0);
    const float2 wv3 = *(const float2*)(we + 3 * HH + j0);

    float acc0 = 0.f, acc1 = 0.f;
    if (c > 0) {
        float4 f_cur = ef4[start];
        unsigned int a_cur = *(const unsigned int*)(XAb + (size_t)es[start] * HH + j0);
        for (int k = start; k < end; ++k) {
            const float4 f = f_cur;
            const float2 a = bfpair2f(a_cur);
            if (k + 1 < end) {
                const int sn = es[k + 1];
                f_cur = ef4[k + 1];
                a_cur = *(const unsigned int*)(XAb + (size_t)sn * HH + j0);
            }
            float h0 = a.x + base0;
            float h1 = a.y + base1;
            h0 = fmaf(f.x, wv0.x, h0); h0 = fmaf(f.y, wv1.x, h0);
            h0 = fmaf(f.z, wv2.x, h0); h0 = fmaf(f.w, wv3.x, h0);
            h1 = fmaf(f.x, wv0.y, h1); h1 = fmaf(f.y, wv1.y, h1);
            h1 = fmaf(f.z, wv2.y, h1); h1 = fmaf(f.w, wv3.y, h1);
            acc0 += fmaxf(h0, 0.f);
            acc1 += fmaxf(h1, 0.f);
        }
    }
    *(float2*)(Hagg + (size_t)d * HH + j0) = make_float2(acc0, acc1);
    if (lane == 0) deg[d] = (float)c;
}

// ---------------------------------------------------------------------------
// Fallback edge kernel (atomic path)
// ---------------------------------------------------------------------------
__global__ __launch_bounds__(256) void k_edge_atomic(const int* __restrict__ ei,
                                                     const float* __restrict__ ef,
                                                     const float* __restrict__ W1,
                                                     const float* __restrict__ b1,
                                                     const unsigned short* __restrict__ XAb,
                                                     const float* __restrict__ XB,
                                                     float* __restrict__ Hagg,
                                                     float* __restrict__ deg) {
    const int wave = threadIdx.x >> 6;
    const int lane = threadIdx.x & 63;
    const long e = (long)blockIdx.x * 4 + wave;
    if (e >= NE) return;
    const int s = ei[e];
    const int d = ei[NE + e];

    float t = 0.f;
    if (lane < DE) t = log1pf(ef[e * DE + lane]);
    const float l0 = __shfl(t, 0);
    const float l1 = __shfl(t, 1);
    const float l2 = __shfl(t, 2);
    const float l3 = __shfl(t, 3);

    const float* we = W1 + 128 * HH;
    const size_t sb = (size_t)s * HH;
    const size_t db = (size_t)d * HH;
#pragma unroll
    for (int r = 0; r < 2; ++r) {
        const int j = lane + r * 64;
        float h = bf2f(XAb[sb + j]) + XB[db + j] + b1[j];
        h = fmaf(l0, we[0 * HH + j], h);
        h = fmaf(l1, we[1 * HH + j], h);
        h = fmaf(l2, we[2 * HH + j], h);
        h = fmaf(l3, we[3 * HH + j], h);
        h = fmaxf(h, 0.f);
        atomicAdd(&Hagg[db + j], h);
    }
    if (lane == 0) atomicAdd(&deg[d], 1.f);
}

// ---------------------------------------------------------------------------
// Kernel 3 (folded): NT2=64 nodes/block, 48 KB LDS (uT aliased into actT).
//   A: u  = relu(x @ U1[:64] + Hagg @ Wc + deg*cvec + bu1)   (K=192 -> 128)
//      tile: 4 nodes x 8 cols per thread -> 32 FMA per ds_read_b128
//   B: out = u @ U2 + bu2                                    (K=128 -> 64)
//      tile: 4 nodes x 4 cols per thread
// ---------------------------------------------------------------------------
__global__ __launch_bounds__(256) void k_update(const float* __restrict__ x,
                                                const float* __restrict__ Hagg,
                                                const float* __restrict__ deg,
                                                const float* __restrict__ U1,
                                                const float* __restrict__ Wc,
                                                const float* __restrict__ cvec,
                                                const float* __restrict__ bu1,
                                                const float* __restrict__ U2,
                                                const float* __restrict__ bu2,
                                                float* __restrict__ out) {
    __shared__ float actT[192][NT2];   // rows 0-63 x^T, 64-191 Hagg^T; rows 0-127 reused as u^T
    __shared__ float sdeg[NT2];
    const int n0 = blockIdx.x * NT2;
    const int t  = threadIdx.x;

    // stage x^T: node i = t&63, k-range (t>>6)*16
    {
        const int i  = t & 63;
        const int k0 = (t >> 6) * 16;
        const int n  = n0 + i;
        if (n < NN) {
            const float4* src = (const float4*)(x + (size_t)n * DN + k0);
#pragma unroll
            for (int q = 0; q < 4; ++q) {
                float4 v = src[q];
                actT[k0 + q * 4 + 0][i] = v.x;
                actT[k0 + q * 4 + 1][i] = v.y;
                actT[k0 + q * 4 + 2][i] = v.z;
                actT[k0 + q * 4 + 3][i] = v.w;
            }
        } else {
#pragma unroll
            for (int q = 0; q < 16; ++q) actT[k0 + q][i] = 0.f;
        }
    }
    // stage Hagg^T into rows 64..191: node i = t&63, k-range (t>>6)*32
    {
        const int i  = t & 63;
        const int k0 = (t >> 6) * 32;
        const int n  = n0 + i;
        if (n < NN) {
            const float4* src = (const float4*)(Hagg + (size_t)n * HH + k0);
#pragma unroll
            for (int q = 0; q < 8; ++q) {
                float4 v = src[q];
                actT[DN + k0 + q * 4 + 0][i] = v.x;
                actT[DN + k0 + q * 4 + 1][i] = v.y;
                actT[DN + k0 + q * 4 + 2][i] = v.z;
                actT[DN + k0 + q * 4 + 3][i] = v.w;
            }
        } else {
#pragma unroll
            for (int q = 0; q < 32; ++q) actT[DN + k0 + q][i] = 0.f;
        }
    }
    if (t < NT2) sdeg[t] = (n0 + t < NN) ? deg[n0 + t] : 0.f;
    __syncthreads();

    const int ng = t & 15;    // 16 groups * 4 nodes
    const int cg = t >> 4;    // 16 groups * 8 cols
    const int cA = cg * 8;

    // ---- Phase A: u = relu(x@U1a + Hagg@Wc + deg*cvec + bu1) ----
    float acc[4][8];
    {
        const float4 bb0 = *(const float4*)(bu1 + cA);
        const float4 bb1 = *(const float4*)(bu1 + cA + 4);
        const float4 cv0 = *(const float4*)(cvec + cA);
        const float4 cv1 = *(const float4*)(cvec + cA + 4);
        const float bbv[8] = {bb0.x, bb0.y, bb0.z, bb0.w, bb1.x, bb1.y, bb1.z, bb1.w};
        const float cvv[8] = {cv0.x, cv0.y, cv0.z, cv0.w, cv1.x, cv1.y, cv1.z, cv1.w};
#pragma unroll
        for (int i = 0; i < 4; ++i) {
            const float dgv = sdeg[ng * 4 + i];
#pragma unroll
            for (int c = 0; c < 8; ++c) acc[i][c] = fmaf(dgv, cvv[c], bbv[c]);
        }
        // K1: x part (U1 rows 0..63) with 1-deep weight prefetch
        const float* wp = U1 + cA;
        float4 w0n = *(const float4*)(wp);
        float4 w1n = *(const float4*)(wp + 4);
#pragma unroll 4
        for (int k = 0; k < DN; ++k) {
            const float4 w0 = w0n;
            const float4 w1 = w1n;
            if (k + 1 < DN) {
                w0n = *(const float4*)(wp + (size_t)(k + 1) * HH);
                w1n = *(const float4*)(wp + (size_t)(k + 1) * HH + 4);
            }
            float4 a = *(const float4*)&actT[k][ng * 4];
            const float ai[4] = {a.x, a.y, a.z, a.w};
            const float wv[8] = {w0.x, w0.y, w0.z, w0.w, w1.x, w1.y, w1.z, w1.w};
#pragma unroll
            for (int i = 0; i < 4; ++i)
#pragma unroll
                for (int c = 0; c < 8; ++c) acc[i][c] = fmaf(ai[i], wv[c], acc[i][c]);
        }
        // K2: Hagg part (Wc rows 0..127) with 1-deep weight prefetch
        const float* wp2 = Wc + cA;
        w0n = *(const float4*)(wp2);
        w1n = *(const float4*)(wp2 + 4);
#pragma unroll 4
        for (int k = 0; k < HH; ++k) {
            const float4 w0 = w0n;
            const float4 w1 = w1n;
            if (k + 1 < HH) {
                w0n = *(const float4*)(wp2 + (size_t)(k + 1) * HH);
                w1n = *(const float4*)(wp2 + (size_t)(k + 1) * HH + 4);
            }
            float4 a = *(const float4*)&actT[DN + k][ng * 4];
            const float ai[4] = {a.x, a.y, a.z, a.w};
            const float wv[8] = {w0.x, w0.y, w0.z, w0.w, w1.x, w1.y, w1.z, w1.w};
#pragma unroll
            for (int i = 0; i < 4; ++i)
#pragma unroll
                for (int c = 0; c < 8; ++c) acc[i][c] = fmaf(ai[i], wv[c], acc[i][c]);
        }
    }
    __syncthreads();   // all reads of actT complete -> safe to overwrite rows 0..127

    // write u^T into actT rows 0..127
#pragma unroll
    for (int c = 0; c < 8; ++c) {
        *(float4*)&actT[cA + c][ng * 4] =
            make_float4(fmaxf(acc[0][c], 0.f), fmaxf(acc[1][c], 0.f),
                        fmaxf(acc[2][c], 0.f), fmaxf(acc[3][c], 0.f));
    }
    __syncthreads();

    // ---- Phase B: out = u @ U2 + bu2 ----
    {
        const int cgB = t & 15;   // 16 groups * 4 cols (fast dim -> coalesced store)
        const int ngB = t >> 4;   // 16 groups * 4 nodes
        const int c0 = cgB * 4;
        const float4 bb = *(const float4*)(bu2 + c0);
        float accB[4][4];
#pragma unroll
        for (int i = 0; i < 4; ++i) {
            accB[i][0] = bb.x; accB[i][1] = bb.y; accB[i][2] = bb.z; accB[i][3] = bb.w;
        }
        const float* wp = U2 + c0;
        float4 w_nxt = *(const float4*)(wp);
#pragma unroll 4
        for (int k = 0; k < HH; ++k) {
            const float4 w = w_nxt;
            if (k + 1 < HH) w_nxt = *(const float4*)(wp + (size_t)(k + 1) * DN);
            float4 u = *(const float4*)&actT[k][ngB * 4];
            const float ui[4] = {u.x, u.y, u.z, u.w};
            const float wc4[4] = {w.x, w.y, w.z, w.w};
#pragma unroll
            for (int i = 0; i < 4; ++i)
#pragma unroll
                for (int c = 0; c < 4; ++c) accB[i][c] = fmaf(ui[i], wc4[c], accB[i][c]);
        }
#pragma unroll
        for (int i = 0; i < 4; ++i) {
            const int n = n0 + ngB * 4 + i;
            if (n < NN) {
                *(float4*)(out + (size_t)n * DN + c0) =
                    make_float4(accB[i][0], accB[i][1], accB[i][2], accB[i][3]);
            }
        }
    }
}

extern "C" void kernel_launch(void* const* d_in, const int* in_sizes, int n_in,
                              void* d_out, int out_size, void* d_ws, size_t ws_size,
                              hipStream_t stream) {
    const float* x   = (const float*)d_in[0];
    const int*   ei  = (const int*)d_in[1];
    const float* ef  = (const float*)d_in[2];
    const float* W1  = (const float*)d_in[3];
    const float* b1  = (const float*)d_in[4];
    const float* W2  = (const float*)d_in[5];
    const float* b2  = (const float*)d_in[6];
    const float* U1  = (const float*)d_in[7];
    const float* bu1 = (const float*)d_in[8];
    const float* U2  = (const float*)d_in[9];
    const float* bu2 = (const float*)d_in[10];
    float* out = (float*)d_out;

    unsigned short* XAb = (unsigned short*)d_ws;       // [NN,128] bf16
    float* XB   = (float*)(XAb + (size_t)NN * HH);     // [NN,128] f32
    float* Hagg = XB + (size_t)NN * HH;                // [NN,128]
    float* deg  = Hagg + (size_t)NN * HH;              // [NN]
    float* Wc   = deg + NN;                            // [128,128]
    float* cvec = Wc + (size_t)HH * HH;                // [128]
    int*   cnt  = (int*)(cvec + HH);                   // [NN]
    int*   pos  = cnt + NN;                            // [NN]
    int*   boff = pos + NN;                            // [1024]
    int*   es   = boff + 1024;                         // [NE]
    float4* ef4 = (float4*)(es + NE);                  // [NE]
    const size_t need = (size_t)((char*)(ef4 + NE) - (char*)d_ws);

    const int nblk  = (NN + NT - 1) / NT;
    const int nblk2 = (NN + NT2 - 1) / NT2;

    k_fold<<<65, 256, 0, stream>>>(W2, U1, b2, Wc, cvec);

    if (ws_size >= need) {
        hipMemsetAsync(cnt, 0, (size_t)NN * sizeof(int), stream);
        k_xproj<<<nblk, 256, 0, stream>>>(x, W1, XAb, XB);
        k_hist<<<(NE + 255) / 256, 256, 0, stream>>>(ei, cnt);
        k_scan_a<<<NBLK_SCAN, SCAN_B, 0, stream>>>(cnt, pos, boff);
        k_scan_b<<<1, 512, 0, stream>>>(boff);
        k_scatter<<<(NE + 255) / 256, 256, 0, stream>>>(ei, ef, pos, boff, es, ef4);
        k_agg<<<(NN + 3) / 4, 256, 0, stream>>>(es, ef4, pos, boff, cnt, XAb, XB, W1, b1, Hagg, deg);
    } else {
        hipMemsetAsync(Hagg, 0, ((size_t)NN * HH + NN) * sizeof(float), stream);
        k_xproj<<<nblk, 256, 0, stream>>>(x, W1, XAb, XB);
        k_edge_atomic<<<NE / 4, 256, 0, stream>>>(ei, ef, W1, b1, XAb, XB, Hagg, deg);
    }
    k_update<<<nblk2, 256, 0, stream>>>(x, Hagg, deg, U1, Wc, cvec, bu1, U2, bu2, out);
}

// Round 8
// 377.953 us; speedup vs baseline: 2.7615x; 1.2132x over previous
//
#include <hip/hip_runtime.h>
#include <math.h>

#define NN 100000       // N_NODES
#define NE 800000       // N_EDGES
#define DN 64           // D_NODE
#define DE 4            // D_EDGE
#define HH 128          // H_MSG == H_UPD
#define NT 64           // nodes per block (k_xproj)
#define NT2 64          // nodes per block (k_update, MFMA)
#define SCAN_B 256
#define NBLK_SCAN ((NN + SCAN_B - 1) / SCAN_B)   // 391

using bf16x8 = __attribute__((ext_vector_type(8))) short;
using f32x4  = __attribute__((ext_vector_type(4))) float;

// bf16 helpers (manual, RNE)
__device__ __forceinline__ unsigned short f2bf(float f) {
    unsigned int u = __float_as_uint(f);
    unsigned int r = (u + 0x7fffu + ((u >> 16) & 1u)) >> 16;
    return (unsigned short)r;
}
__device__ __forceinline__ float bf2f(unsigned short h) {
    return __uint_as_float(((unsigned int)h) << 16);
}
__device__ __forceinline__ float2 bfpair2f(unsigned int v) {
    return make_float2(__uint_as_float(v << 16),
                       __uint_as_float(v & 0xffff0000u));
}

// ---------------------------------------------------------------------------
// Kernel 1: XA(bf16) = x @ W1[0:64,:], XB(f32) = x @ W1[64:128,:]
// ---------------------------------------------------------------------------
__global__ __launch_bounds__(256) void k_xproj(const float* __restrict__ x,
                                               const float* __restrict__ W1,
                                               unsigned short* __restrict__ XAb,
                                               float* __restrict__ XB) {
    __shared__ float xsT[DN][NT];
    const int n0 = blockIdx.x * NT;
    const int t  = threadIdx.x;
    {
        const int i  = t & 63;
        const int k0 = (t >> 6) * 16;
        const int n  = n0 + i;
        if (n < NN) {
            const float4* src = (const float4*)(x + (size_t)n * DN + k0);
#pragma unroll
            for (int q = 0; q < 4; ++q) {
                float4 v = src[q];
                xsT[k0 + q * 4 + 0][i] = v.x;
                xsT[k0 + q * 4 + 1][i] = v.y;
                xsT[k0 + q * 4 + 2][i] = v.z;
                xsT[k0 + q * 4 + 3][i] = v.w;
            }
        } else {
#pragma unroll
            for (int q = 0; q < 16; ++q) xsT[k0 + q][i] = 0.f;
        }
    }
    __syncthreads();

    const int cg = t & 31;
    const int ng = t >> 5;
    const int c0 = cg * 8;
    const float* wbase = (c0 < HH) ? (W1 + c0) : (W1 + (size_t)DN * HH + (c0 - HH));

    float acc[8][8];
#pragma unroll
    for (int i = 0; i < 8; ++i)
#pragma unroll
        for (int c = 0; c < 8; ++c) acc[i][c] = 0.f;

#pragma unroll 2
    for (int k = 0; k < DN; ++k) {
        float4 xa = *(const float4*)&xsT[k][ng * 8];
        float4 xb = *(const float4*)&xsT[k][ng * 8 + 4];
        float4 w0 = *(const float4*)(wbase + (size_t)k * HH);
        float4 w1 = *(const float4*)(wbase + (size_t)k * HH + 4);
        const float xi[8] = {xa.x, xa.y, xa.z, xa.w, xb.x, xb.y, xb.z, xb.w};
        const float wc[8] = {w0.x, w0.y, w0.z, w0.w, w1.x, w1.y, w1.z, w1.w};
#pragma unroll
        for (int i = 0; i < 8; ++i)
#pragma unroll
            for (int c = 0; c < 8; ++c) acc[i][c] = fmaf(xi[i], wc[c], acc[i][c]);
    }

    if (c0 < HH) {
#pragma unroll
        for (int i = 0; i < 8; ++i) {
            const int n = n0 + ng * 8 + i;
            if (n < NN) {
                unsigned short tmp[8];
#pragma unroll
                for (int c = 0; c < 8; ++c) tmp[c] = f2bf(acc[i][c]);
                *(uint4*)(XAb + (size_t)n * HH + c0) = *(const uint4*)tmp;
            }
        }
    } else {
#pragma unroll
        for (int i = 0; i < 8; ++i) {
            const int n = n0 + ng * 8 + i;
            if (n < NN) {
                float* dst = XB + (size_t)n * HH + (c0 - HH);
                *(float4*)(dst)     = make_float4(acc[i][0], acc[i][1], acc[i][2], acc[i][3]);
                *(float4*)(dst + 4) = make_float4(acc[i][4], acc[i][5], acc[i][6], acc[i][7]);
            }
        }
    }
}

// ---------------------------------------------------------------------------
// Fold kernel: Wc = W2 @ U1[64:128,:];  cvec = b2 @ U1[64:128,:]
// ---------------------------------------------------------------------------
__global__ __launch_bounds__(256) void k_fold(const float* __restrict__ W2,
                                              const float* __restrict__ U1,
                                              const float* __restrict__ b2,
                                              float* __restrict__ Wc,
                                              float* __restrict__ cvec) {
    const int idx = blockIdx.x * 256 + threadIdx.x;
    const float* u1b = U1 + (size_t)DN * HH;
    if (blockIdx.x < 64) {
        const int r = idx >> 7;
        const int c = idx & 127;
        float acc = 0.f;
#pragma unroll 8
        for (int j = 0; j < DN; ++j)
            acc = fmaf(W2[(size_t)r * DN + j], u1b[(size_t)j * HH + c], acc);
        Wc[(size_t)r * HH + c] = acc;
    } else if (threadIdx.x < HH) {
        const int c = threadIdx.x;
        float acc = 0.f;
#pragma unroll 8
        for (int j = 0; j < DN; ++j)
            acc = fmaf(b2[j], u1b[(size_t)j * HH + c], acc);
        cvec[c] = acc;
    }
}

// ---------------------------------------------------------------------------
// Pack kernel: weights -> bf16 B-fragment layout for mfma_f32_16x16x32_bf16.
// B-frag: lane l holds B[k = kb*32 + (l>>4)*8 + j][n = ntile*16 + (l&15)].
// Wpa: phase-A weights W_A[192][128] = [U1[0:64] ; Wc]  -> [n(8)][kb(6)][l(64)][j(8)]
// Wpb: phase-B weights U2[128][64]                      -> [n(4)][kb(4)][l(64)][j(8)]
// ---------------------------------------------------------------------------
__global__ __launch_bounds__(256) void k_pack(const float* __restrict__ U1,
                                              const float* __restrict__ Wc,
                                              const float* __restrict__ U2,
                                              unsigned short* __restrict__ Wpa,
                                              unsigned short* __restrict__ Wpb) {
    const int tid = blockIdx.x * 256 + threadIdx.x;
    if (tid < 3072) {
        const int l  = tid & 63;
        const int kb = (tid >> 6) % 6;
        const int n  = tid / 384;
        const int kbase = kb * 32 + (l >> 4) * 8;
        const int col   = n * 16 + (l & 15);
        unsigned short tmp[8];
#pragma unroll
        for (int j = 0; j < 8; ++j) {
            const int k = kbase + j;
            const float v = (k < DN) ? U1[(size_t)k * HH + col]
                                     : Wc[(size_t)(k - DN) * HH + col];
            tmp[j] = f2bf(v);
        }
        *(uint4*)(Wpa + (size_t)tid * 8) = *(const uint4*)tmp;
    } else if (tid < 4096) {
        const int t2 = tid - 3072;
        const int l  = t2 & 63;
        const int kb = (t2 >> 6) & 3;
        const int n2 = t2 >> 8;
        const int kbase = kb * 32 + (l >> 4) * 8;
        const int col   = n2 * 16 + (l & 15);
        unsigned short tmp[8];
#pragma unroll
        for (int j = 0; j < 8; ++j) tmp[j] = f2bf(U2[(size_t)(kbase + j) * DN + col]);
        *(uint4*)(Wpb + (size_t)t2 * 8) = *(const uint4*)tmp;
    }
}

// ---------------------------------------------------------------------------
// Counting sort by destination
// ---------------------------------------------------------------------------
__global__ __launch_bounds__(256) void k_hist(const int* __restrict__ ei,
                                              int* __restrict__ cnt) {
    const int e = blockIdx.x * 256 + threadIdx.x;
    if (e < NE) atomicAdd(&cnt[ei[NE + e]], 1);
}

__global__ __launch_bounds__(SCAN_B) void k_scan_a(const int* __restrict__ cnt,
                                                   int* __restrict__ pos,
                                                   int* __restrict__ bsum) {
    __shared__ int sh[SCAN_B];
    const int n = blockIdx.x * SCAN_B + threadIdx.x;
    const int c = (n < NN) ? cnt[n] : 0;
    sh[threadIdx.x] = c;
    __syncthreads();
    int v = c;
#pragma unroll
    for (int off = 1; off < SCAN_B; off <<= 1) {
        int add = (threadIdx.x >= off) ? sh[threadIdx.x - off] : 0;
        __syncthreads();
        v += add;
        sh[threadIdx.x] = v;
        __syncthreads();
    }
    if (n < NN) pos[n] = v - c;
    if (threadIdx.x == SCAN_B - 1) bsum[blockIdx.x] = v;
}

__global__ __launch_bounds__(512) void k_scan_b(int* __restrict__ bsum) {
    __shared__ int sh[512];
    const int i = threadIdx.x;
    const int c = (i < NBLK_SCAN) ? bsum[i] : 0;
    sh[i] = c;
    __syncthreads();
    int v = c;
#pragma unroll
    for (int off = 1; off < 512; off <<= 1) {
        int add = (i >= off) ? sh[i - off] : 0;
        __syncthreads();
        v += add;
        sh[i] = v;
        __syncthreads();
    }
    if (i < NBLK_SCAN) bsum[i] = v - c;
}

__global__ __launch_bounds__(256) void k_scatter(const int* __restrict__ ei,
                                                 const float* __restrict__ ef,
                                                 int* __restrict__ pos,
                                                 const int* __restrict__ boff,
                                                 int* __restrict__ es,
                                                 float4* __restrict__ ef4) {
    const int e = blockIdx.x * 256 + threadIdx.x;
    if (e >= NE) return;
    const int s = ei[e];
    const int d = ei[NE + e];
    const int slot = atomicAdd(&pos[d], 1) + boff[d >> 8];
    es[slot] = s;
    ef4[slot] = make_float4(log1pf(ef[e * 4 + 0]), log1pf(ef[e * 4 + 1]),
                            log1pf(ef[e * 4 + 2]), log1pf(ef[e * 4 + 3]));
}

// ---------------------------------------------------------------------------
// Segmented reduce, one wave per node (unchanged from R7).
// ---------------------------------------------------------------------------
__global__ __launch_bounds__(256) void k_agg(const int* __restrict__ es,
                                             const float4* __restrict__ ef4,
                                             const int* __restrict__ pos,
                                             const int* __restrict__ boff,
                                             const int* __restrict__ cnt,
                                             const unsigned short* __restrict__ XAb,
                                             const float* __restrict__ XB,
                                             const float* __restrict__ W1,
                                             const float* __restrict__ b1,
                                             float* __restrict__ Hagg,
                                             float* __restrict__ deg) {
    const int wave = threadIdx.x >> 6;
    const int lane = threadIdx.x & 63;
    const int d = blockIdx.x * 4 + wave;
    if (d >= NN) return;
    const int c     = cnt[d];
    const int end   = pos[d] + boff[d >> 8];
    const int start = end - c;
    const int j0    = lane * 2;

    const float* we = W1 + 128 * HH;
    const float2 xb = *(const float2*)(XB + (size_t)d * HH + j0);
    const float2 bb = *(const float2*)(b1 + j0);
    const float base0 = xb.x + bb.x;
    const float base1 = xb.y + bb.y;
    const float2 wv0 = *(const float2*)(we + 0 * HH + j0);
    const float2 wv1 = *(const float2*)(we + 1 * HH + j0);
    const float2 wv2 = *(const float2*)(we + 2 * HH + j0);
    const float2 wv3 = *(const float2*)(we + 3 * HH + j0);

    float acc0 = 0.f, acc1 = 0.f;
    if (c > 0) {
        float4 f_cur = ef4[start];
        unsigned int a_cur = *(const unsigned int*)(XAb + (size_t)es[start] * HH + j0);
        for (int k = start; k < end; ++k) {
            const float4 f = f_cur;
            const float2 a = bfpair2f(a_cur);
            if (k + 1 < end) {
                const int sn = es[k + 1];
                f_cur = ef4[k + 1];
                a_cur = *(const unsigned int*)(XAb + (size_t)sn * HH + j0);
            }
            float h0 = a.x + base0;
            float h1 = a.y + base1;
            h0 = fmaf(f.x, wv0.x, h0); h0 = fmaf(f.y, wv1.x, h0);
            h0 = fmaf(f.z, wv2.x, h0); h0 = fmaf(f.w, wv3.x, h0);
            h1 = fmaf(f.x, wv0.y, h1); h1 = fmaf(f.y, wv1.y, h1);
            h1 = fmaf(f.z, wv2.y, h1); h1 = fmaf(f.w, wv3.y, h1);
            acc0 += fmaxf(h0, 0.f);
            acc1 += fmaxf(h1, 0.f);
        }
    }
    *(float2*)(Hagg + (size_t)d * HH + j0) = make_float2(acc0, acc1);
    if (lane == 0) deg[d] = (float)c;
}

// ---------------------------------------------------------------------------
// Fallback edge kernel (atomic path)
// ---------------------------------------------------------------------------
__global__ __launch_bounds__(256) void k_edge_atomic(const int* __restrict__ ei,
                                                     const float* __restrict__ ef,
                                                     const float* __restrict__ W1,
                                                     const float* __restrict__ b1,
                                                     const unsigned short* __restrict__ XAb,
                                                     const float* __restrict__ XB,
                                                     float* __restrict__ Hagg,
                                                     float* __restrict__ deg) {
    const int wave = threadIdx.x >> 6;
    const int lane = threadIdx.x & 63;
    const long e = (long)blockIdx.x * 4 + wave;
    if (e >= NE) return;
    const int s = ei[e];
    const int d = ei[NE + e];

    float t = 0.f;
    if (lane < DE) t = log1pf(ef[e * DE + lane]);
    const float l0 = __shfl(t, 0);
    const float l1 = __shfl(t, 1);
    const float l2 = __shfl(t, 2);
    const float l3 = __shfl(t, 3);

    const float* we = W1 + 128 * HH;
    const size_t sb = (size_t)s * HH;
    const size_t db = (size_t)d * HH;
#pragma unroll
    for (int r = 0; r < 2; ++r) {
        const int j = lane + r * 64;
        float h = bf2f(XAb[sb + j]) + XB[db + j] + b1[j];
        h = fmaf(l0, we[0 * HH + j], h);
        h = fmaf(l1, we[1 * HH + j], h);
        h = fmaf(l2, we[2 * HH + j], h);
        h = fmaf(l3, we[3 * HH + j], h);
        h = fmaxf(h, 0.f);
        atomicAdd(&Hagg[db + j], h);
    }
    if (lane == 0) atomicAdd(&deg[d], 1.f);
}

// ---------------------------------------------------------------------------
// Kernel 3 (MFMA): 64 nodes/block, 4 waves, one 16-row m-tile per wave.
//   A: u  = relu([x|Hagg] @ W_A + deg*cvec + bu1)   (K=192, N=128, bf16 MFMA)
//   B: out = u @ U2 + bu2                           (K=128, N=64,  bf16 MFMA)
// LDS: sA = activations in A-frag layout (24 KB), aliased as u-buffer for B.
// A-frag: lane l holds A[m = l&15][k = kb*32 + (l>>4)*8 + j]  (m89/m120)
// C/D:    col = l&15, row = (l>>4)*4 + reg                     (m89/m91)
// ---------------------------------------------------------------------------
__global__ __launch_bounds__(256) void k_update(const float* __restrict__ x,
                                                const float* __restrict__ Hagg,
                                                const float* __restrict__ deg,
                                                const unsigned short* __restrict__ Wpa,
                                                const unsigned short* __restrict__ Wpb,
                                                const float* __restrict__ cvec,
                                                const float* __restrict__ bu1,
                                                const float* __restrict__ bu2,
                                                float* __restrict__ out) {
    __shared__ unsigned short sA[6 * 4 * 64 * 8];   // 24 KB; [Q=kb*4+quad][m 0..63][j 0..7]
    __shared__ float sdeg[NT2];
    const int n0 = blockIdx.x * NT2;
    const int t  = threadIdx.x;
    const int w    = t >> 6;
    const int l    = t & 63;
    const int quad = l >> 4;
    const int l16  = l & 15;

    // ---- stage x (k=0..63) as bf16 into A-frag layout ----
#pragma unroll
    for (int it = 0; it < 4; ++it) {
        const int flat = t + it * 256;        // 0..1023 = node*16 + c
        const int node = flat >> 4;
        const int c    = flat & 15;
        const int gn   = n0 + node;
        float4 v = make_float4(0.f, 0.f, 0.f, 0.f);
        if (gn < NN) v = *(const float4*)(x + (size_t)gn * DN + c * 4);
        const int k = c * 4, Q = k >> 3, j0 = k & 7;
        uint2 pk;
        pk.x = (unsigned)f2bf(v.x) | ((unsigned)f2bf(v.y) << 16);
        pk.y = (unsigned)f2bf(v.z) | ((unsigned)f2bf(v.w) << 16);
        *(uint2*)(&sA[(Q * 64 + node) * 8 + j0]) = pk;
    }
    // ---- stage Hagg (k=64..191) ----
#pragma unroll
    for (int it = 0; it < 8; ++it) {
        const int flat = t + it * 256;        // 0..2047 = node*32 + c
        const int node = flat >> 5;
        const int c    = flat & 31;
        const int gn   = n0 + node;
        float4 v = make_float4(0.f, 0.f, 0.f, 0.f);
        if (gn < NN) v = *(const float4*)(Hagg + (size_t)gn * HH + c * 4);
        const int k = DN + c * 4, Q = k >> 3, j0 = k & 7;
        uint2 pk;
        pk.x = (unsigned)f2bf(v.x) | ((unsigned)f2bf(v.y) << 16);
        pk.y = (unsigned)f2bf(v.z) | ((unsigned)f2bf(v.w) << 16);
        *(uint2*)(&sA[(Q * 64 + node) * 8 + j0]) = pk;
    }
    if (t < NT2) sdeg[t] = (n0 + t < NN) ? deg[n0 + t] : 0.f;
    __syncthreads();

    // ---- Phase A: 8 n-tiles, K=192 (6 kb) ----
    f32x4 acc[8];
#pragma unroll
    for (int n = 0; n < 8; ++n) {
        const int col = n * 16 + l16;
        const float bv = bu1[col];
        const float cv = cvec[col];
#pragma unroll
        for (int r = 0; r < 4; ++r)
            acc[n][r] = fmaf(sdeg[w * 16 + quad * 4 + r], cv, bv);
    }
    const int mrow = w * 16 + l16;
#pragma unroll
    for (int kb = 0; kb < 6; ++kb) {
        bf16x8 a = *(const bf16x8*)(const void*)(&sA[((kb * 4 + quad) * 64 + mrow) * 8]);
#pragma unroll
        for (int n = 0; n < 8; ++n) {
            bf16x8 b = *(const bf16x8*)(const void*)(Wpa + ((size_t)(n * 6 + kb) * 64 + l) * 8);
            acc[n] = __builtin_amdgcn_mfma_f32_16x16x32_bf16(a, b, acc[n], 0, 0, 0);
        }
    }
    __syncthreads();   // all sA reads done -> reuse as u buffer

    // ---- write u (relu, bf16) into A-frag layout for phase B (K=128) ----
#pragma unroll
    for (int n = 0; n < 8; ++n) {
        const int col = n * 16 + l16;
        const int Q = col >> 3;
        const int j = col & 7;
#pragma unroll
        for (int r = 0; r < 4; ++r) {
            const int m = w * 16 + quad * 4 + r;
            sA[(Q * 64 + m) * 8 + j] = f2bf(fmaxf(acc[n][r], 0.f));
        }
    }
    __syncthreads();

    // ---- Phase B: 4 n-tiles, K=128 (4 kb) ----
    f32x4 acc2[4];
#pragma unroll
    for (int n2 = 0; n2 < 4; ++n2) {
        const float bv = bu2[n2 * 16 + l16];
        acc2[n2][0] = bv; acc2[n2][1] = bv; acc2[n2][2] = bv; acc2[n2][3] = bv;
    }
#pragma unroll
    for (int kb = 0; kb < 4; ++kb) {
        bf16x8 a = *(const bf16x8*)(const void*)(&sA[((kb * 4 + quad) * 64 + mrow) * 8]);
#pragma unroll
        for (int n2 = 0; n2 < 4; ++n2) {
            bf16x8 b = *(const bf16x8*)(const void*)(Wpb + ((size_t)(n2 * 4 + kb) * 64 + l) * 8);
            acc2[n2] = __builtin_amdgcn_mfma_f32_16x16x32_bf16(a, b, acc2[n2], 0, 0, 0);
        }
    }
    // ---- store out ----
#pragma unroll
    for (int n2 = 0; n2 < 4; ++n2) {
        const int col = n2 * 16 + l16;
#pragma unroll
        for (int r = 0; r < 4; ++r) {
            const int gn = n0 + w * 16 + quad * 4 + r;
            if (gn < NN) out[(size_t)gn * DN + col] = acc2[n2][r];
        }
    }
}

extern "C" void kernel_launch(void* const* d_in, const int* in_sizes, int n_in,
                              void* d_out, int out_size, void* d_ws, size_t ws_size,
                              hipStream_t stream) {
    const float* x   = (const float*)d_in[0];
    const int*   ei  = (const int*)d_in[1];
    const float* ef  = (const float*)d_in[2];
    const float* W1  = (const float*)d_in[3];
    const float* b1  = (const float*)d_in[4];
    const float* W2  = (const float*)d_in[5];
    const float* b2  = (const float*)d_in[6];
    const float* U1  = (const float*)d_in[7];
    const float* bu1 = (const float*)d_in[8];
    const float* U2  = (const float*)d_in[9];
    const float* bu2 = (const float*)d_in[10];
    float* out = (float*)d_out;

    unsigned short* XAb = (unsigned short*)d_ws;       // [NN,128] bf16
    float* XB   = (float*)(XAb + (size_t)NN * HH);     // [NN,128] f32
    float* Hagg = XB + (size_t)NN * HH;                // [NN,128]
    float* deg  = Hagg + (size_t)NN * HH;              // [NN]
    float* Wc   = deg + NN;                            // [128,128]
    float* cvec = Wc + (size_t)HH * HH;                // [128]
    unsigned short* Wpa = (unsigned short*)(cvec + HH);// [8*6*64*8] bf16 packed
    unsigned short* Wpb = Wpa + 8 * 6 * 64 * 8;        // [4*4*64*8]
    int*   cnt  = (int*)(Wpb + 4 * 4 * 64 * 8);        // [NN]
    int*   pos  = cnt + NN;                            // [NN]
    int*   boff = pos + NN;                            // [1024]
    int*   es   = boff + 1024;                         // [NE]
    float4* ef4 = (float4*)(es + NE);                  // [NE]
    const size_t need = (size_t)((char*)(ef4 + NE) - (char*)d_ws);

    const int nblk  = (NN + NT - 1) / NT;
    const int nblk2 = (NN + NT2 - 1) / NT2;

    k_fold<<<65, 256, 0, stream>>>(W2, U1, b2, Wc, cvec);
    k_pack<<<16, 256, 0, stream>>>(U1, Wc, U2, Wpa, Wpb);

    if (ws_size >= need) {
        hipMemsetAsync(cnt, 0, (size_t)NN * sizeof(int), stream);
        k_xproj<<<nblk, 256, 0, stream>>>(x, W1, XAb, XB);
        k_hist<<<(NE + 255) / 256, 256, 0, stream>>>(ei, cnt);
        k_scan_a<<<NBLK_SCAN, SCAN_B, 0, stream>>>(cnt, pos, boff);
        k_scan_b<<<1, 512, 0, stream>>>(boff);
        k_scatter<<<(NE + 255) / 256, 256, 0, stream>>>(ei, ef, pos, boff, es, ef4);
        k_agg<<<(NN + 3) / 4, 256, 0, stream>>>(es, ef4, pos, boff, cnt, XAb, XB, W1, b1, Hagg, deg);
    } else {
        hipMemsetAsync(Hagg, 0, ((size_t)NN * HH + NN) * sizeof(float), stream);
        k_xproj<<<nblk, 256, 0, stream>>>(x, W1, XAb, XB);
        k_edge_atomic<<<NE / 4, 256, 0, stream>>>(ei, ef, W1, b1, XAb, XB, Hagg, deg);
    }
    k_update<<<nblk2, 256, 0, stream>>>(x, Hagg, deg, Wpa, Wpb, cvec, bu1, bu2, out);
}